// Round 1
// baseline (1324.649 us; speedup 1.0000x reference)
//
#include <hip/hip_runtime.h>

#define NREL 8
#define NNODE 100000
#define TNODE 50000
#define NEDGE 800000
#define C 128
#define TILE_T 64
#define NTILE ((TNODE + TILE_T - 1) / TILE_T)   // 782

__device__ __forceinline__ void fma4(float4& acc, float a, const float4& b) {
    acc.x = fmaf(a, b.x, acc.x);
    acc.y = fmaf(a, b.y, acc.y);
    acc.z = fmaf(a, b.z, acc.z);
    acc.w = fmaf(a, b.w, acc.w);
}
__device__ __forceinline__ void add4(float4& acc, const float4& b) {
    acc.x += b.x; acc.y += b.y; acc.z += b.z; acc.w += b.w;
}

__global__ __launch_bounds__(256, 1)
void rgcn_fused_kernel(const float* __restrict__ x,
                       const float* __restrict__ w,
                       const int* __restrict__ ptr,
                       const int* __restrict__ idx,
                       const int* __restrict__ tgt,
                       float* __restrict__ out)
{
    __shared__ float sW[C * C];               // 64 KB: W_r row-major [k][c]
    __shared__ float sAgg[TILE_T][C + 4];     // 33.8 KB, +4 pad keeps 16B align

    const int tid  = threadIdx.x;
    const int tile = blockIdx.x;
    const int r    = blockIdx.y;

    // ---- stage W_r into LDS (flat float4 copy, coalesced) ----
    {
        const float4* src = (const float4*)(w + (size_t)r * C * C);
        float4* dst = (float4*)sW;
        #pragma unroll
        for (int i = 0; i < (C * C / 4) / 256; ++i)
            dst[tid + i * 256] = src[tid + i * 256];
    }

    // ---- gather: 4 threads per target, 32 cols each, f32 accumulate ----
    {
        const int tl = tid >> 2;      // local target 0..63
        const int g  = tid & 3;       // col group: floats [g*32, g*32+32)
        const int t  = tile * TILE_T + tl;
        float4 a[8];
        #pragma unroll
        for (int j = 0; j < 8; ++j) a[j] = make_float4(0.f, 0.f, 0.f, 0.f);
        if (t < TNODE) {
            const int* pr = ptr + (size_t)r * (TNODE + 1);
            const int* er = idx + (size_t)r * NEDGE;
            // clip(searchsorted(ptr,e,'right')-1, 0, T-1) ==
            //   t==0 takes [0, ptr[1]); t==T-1 takes [ptr[T-1], E)
            int e         = (t == 0)         ? 0     : pr[t];
            const int end = (t == TNODE - 1) ? NEDGE : pr[t + 1];
            for (; e + 2 <= end; e += 2) {
                const int s0 = er[e], s1 = er[e + 1];
                const float4* r0 = (const float4*)(x + (size_t)s0 * C) + g * 8;
                const float4* r1 = (const float4*)(x + (size_t)s1 * C) + g * 8;
                float4 v0[8], v1[8];
                #pragma unroll
                for (int j = 0; j < 8; ++j) v0[j] = r0[j];
                #pragma unroll
                for (int j = 0; j < 8; ++j) v1[j] = r1[j];
                #pragma unroll
                for (int j = 0; j < 8; ++j) add4(a[j], v0[j]);
                #pragma unroll
                for (int j = 0; j < 8; ++j) add4(a[j], v1[j]);
            }
            if (e < end) {
                const int s0 = er[e];
                const float4* r0 = (const float4*)(x + (size_t)s0 * C) + g * 8;
                #pragma unroll
                for (int j = 0; j < 8; ++j) add4(a[j], r0[j]);
            }
        }
        // write agg row chunk to LDS (zeros for out-of-range targets)
        float* rowp = &sAgg[tl][g * 32];
        #pragma unroll
        for (int j = 0; j < 8; ++j) ((float4*)rowp)[j] = a[j];
    }
    __syncthreads();

    // ---- register-blocked f32 GEMM: thread owns 4 targets x 8 cols ----
    // cols are {cg*4..+3} and {64+cg*4..+3} -> W LDS reads <=2-way conflict (free)
    const int tg = tid >> 4;   // 0..15 -> targets tg*4..tg*4+3
    const int cg = tid & 15;
    float4 acc0[4], acc1[4];
    #pragma unroll
    for (int i = 0; i < 4; ++i) {
        acc0[i] = make_float4(0.f, 0.f, 0.f, 0.f);
        acc1[i] = make_float4(0.f, 0.f, 0.f, 0.f);
    }
    for (int k4 = 0; k4 < C / 4; ++k4) {
        float4 av[4];
        #pragma unroll
        for (int i = 0; i < 4; ++i)
            av[i] = *(const float4*)&sAgg[tg * 4 + i][k4 * 4];
        #pragma unroll
        for (int kk = 0; kk < 4; ++kk) {
            const int k = k4 * 4 + kk;
            const float4 w0 = *(const float4*)&sW[k * C + cg * 4];
            const float4 w1 = *(const float4*)&sW[k * C + 64 + cg * 4];
            #pragma unroll
            for (int i = 0; i < 4; ++i) {
                const float a = ((const float*)&av[i])[kk];
                fma4(acc0[i], a, w0);
                fma4(acc1[i], a, w1);
            }
        }
    }

    // ---- scatter-add into out[tgt[t]] ----
    const int* tr = tgt + (size_t)r * TNODE;
    #pragma unroll
    for (int i = 0; i < 4; ++i) {
        const int t = tile * TILE_T + tg * 4 + i;
        if (t < TNODE) {
            const int node = tr[t];
            float* ob = out + (size_t)node * C + cg * 4;
            unsafeAtomicAdd(ob + 0,      acc0[i].x);
            unsafeAtomicAdd(ob + 1,      acc0[i].y);
            unsafeAtomicAdd(ob + 2,      acc0[i].z);
            unsafeAtomicAdd(ob + 3,      acc0[i].w);
            unsafeAtomicAdd(ob + 64 + 0, acc1[i].x);
            unsafeAtomicAdd(ob + 64 + 1, acc1[i].y);
            unsafeAtomicAdd(ob + 64 + 2, acc1[i].z);
            unsafeAtomicAdd(ob + 64 + 3, acc1[i].w);
        }
    }
}

extern "C" void kernel_launch(void* const* d_in, const int* in_sizes, int n_in,
                              void* d_out, int out_size, void* d_ws, size_t ws_size,
                              hipStream_t stream) {
    const float* x   = (const float*)d_in[0];
    const float* w   = (const float*)d_in[1];
    const int*   ptr = (const int*)d_in[2];
    const int*   idx = (const int*)d_in[3];
    const int*   tgt = (const int*)d_in[4];
    float* out = (float*)d_out;

    hipMemsetAsync(out, 0, (size_t)NNODE * C * sizeof(float), stream);

    dim3 grid(NTILE, NREL);
    rgcn_fused_kernel<<<grid, 256, 0, stream>>>(x, w, ptr, idx, tgt, out);
}

// Round 3
// 973.160 us; speedup vs baseline: 1.3612x; 1.3612x over previous
//
#include <hip/hip_runtime.h>

#define NREL 8
#define NNODE 100000
#define TNODE 50000
#define NEDGE 800000
#define C 128
#define TILE_T 64
#define NTILE ((TNODE + TILE_T - 1) / TILE_T)   // 782

typedef unsigned int u32;
typedef unsigned short u16;

__device__ __forceinline__ float bf2f(u16 h) {
    union { u32 u; float f; } c; c.u = ((u32)h) << 16; return c.f;
}
__device__ __forceinline__ u16 f2bf(float f) {
    union { float f; u32 u; } c; c.f = f;
    u32 u = c.u + 0x7FFFu + ((c.u >> 16) & 1u);   // RNE
    return (u16)(u >> 16);
}
__device__ __forceinline__ float2 unpack_bf2(u32 p) {
    union { u32 u; float f; } a, b;
    a.u = p << 16; b.u = p & 0xFFFF0000u;
    return make_float2(a.f, b.f);
}
__device__ __forceinline__ void fma4(float4& acc, float a, float w0, float w1, float w2, float w3) {
    acc.x = fmaf(a, w0, acc.x);
    acc.y = fmaf(a, w1, acc.y);
    acc.z = fmaf(a, w2, acc.z);
    acc.w = fmaf(a, w3, acc.w);
}

// ---------------- kernel 1: x f32 -> bf16 ----------------
__global__ __launch_bounds__(256)
void convert_x_kernel(const float* __restrict__ x, u16* __restrict__ xb, int n4) {
    int i = blockIdx.x * 256 + threadIdx.x;
    const int stride = gridDim.x * 256;
    for (; i < n4; i += stride) {
        const float4 v = ((const float4*)x)[i];
        ushort4 o;
        o.x = f2bf(v.x); o.y = f2bf(v.y); o.z = f2bf(v.z); o.w = f2bf(v.w);
        ((ushort4*)xb)[i] = o;
    }
}

// ---------------- kernel 2: gather-sum, one wave per target ----------------
__global__ __launch_bounds__(256, 6)
void gather_kernel(const u16* __restrict__ xb, const int* __restrict__ ptr,
                   const int* __restrict__ idx, float* __restrict__ agg) {
    const int lane = threadIdx.x & 63;
    const int wid  = threadIdx.x >> 6;
    const int g    = blockIdx.x * 4 + wid;       // global (rel,target) id
    const int r    = g / TNODE;
    const int t    = g - r * TNODE;

    const int* pr = ptr + r * (TNODE + 1);
    const int* er = idx + (size_t)r * NEDGE;
    // clip(searchsorted(ptr,e,'right')-1, 0, T-1):
    //   t==0 owns [0, ptr[1]); t==T-1 owns [ptr[T-1], E)
    const int start = (t == 0) ? 0 : pr[t];
    const int end   = (t == TNODE - 1) ? NEDGE : pr[t + 1];

    float4 acc = make_float4(0.f, 0.f, 0.f, 0.f);
    const int half = lane >> 5;                  // which of 2 concurrent edges
    const int sl   = lane & 31;                  // 4-col chunk within row
    const u16* xcol = xb + sl * 4;

    for (int base = start; base < end; base += 64) {
        const int cnt = min(end - base, 64);
        int myi = (lane < cnt) ? er[base + lane] : 0;
        int i = 0;
        for (; i + 4 <= cnt; i += 4) {          // 4 edges per iter (2 per half-wave)
            const int sA = __shfl(myi, i + half);
            const int sB = __shfl(myi, i + 2 + half);
            const ushort4 vA = *(const ushort4*)(xcol + (size_t)sA * C);
            const ushort4 vB = *(const ushort4*)(xcol + (size_t)sB * C);
            acc.x += bf2f(vA.x); acc.y += bf2f(vA.y);
            acc.z += bf2f(vA.z); acc.w += bf2f(vA.w);
            acc.x += bf2f(vB.x); acc.y += bf2f(vB.y);
            acc.z += bf2f(vB.z); acc.w += bf2f(vB.w);
        }
        if (i + 2 <= cnt) {
            const int sA = __shfl(myi, i + half);
            const ushort4 vA = *(const ushort4*)(xcol + (size_t)sA * C);
            acc.x += bf2f(vA.x); acc.y += bf2f(vA.y);
            acc.z += bf2f(vA.z); acc.w += bf2f(vA.w);
            i += 2;
        }
        if (i < cnt) {
            const int sA = __shfl(myi, i);      // shfl while all lanes active
            if (half == 0) {
                const ushort4 vA = *(const ushort4*)(xcol + (size_t)sA * C);
                acc.x += bf2f(vA.x); acc.y += bf2f(vA.y);
                acc.z += bf2f(vA.z); acc.w += bf2f(vA.w);
            }
        }
    }
    // fold the two half-waves
    acc.x += __shfl_xor(acc.x, 32);
    acc.y += __shfl_xor(acc.y, 32);
    acc.z += __shfl_xor(acc.z, 32);
    acc.w += __shfl_xor(acc.w, 32);
    if (half == 0) {
        float4* dst = (float4*)(agg + (size_t)g * C) + sl;
        *dst = acc;
    }
}

// ---------------- kernel 3: tile GEMM (bf16 W in LDS) + atomic scatter ----------------
__global__ __launch_bounds__(256, 2)
void gemm_scatter_kernel(const float* __restrict__ agg, const float* __restrict__ w,
                         const int* __restrict__ tgt, float* __restrict__ out) {
    __shared__ u16   sW[C * C];             // 32 KB, bf16 [k][c]
    __shared__ float sA[TILE_T][C + 4];     // 33.8 KB, f32 agg tile

    const int tid  = threadIdx.x;
    const int tile = blockIdx.x;
    const int r    = blockIdx.y;

    // stage W_r -> bf16 LDS
    {
        const float4* src = (const float4*)(w + (size_t)r * C * C);
        #pragma unroll
        for (int i = 0; i < 16; ++i) {
            const float4 v = src[tid + i * 256];
            ushort4 o;
            o.x = f2bf(v.x); o.y = f2bf(v.y); o.z = f2bf(v.z); o.w = f2bf(v.w);
            ((ushort4*)sW)[tid + i * 256] = o;
        }
    }
    // stage agg tile (f32)
    {
        const int row = tid >> 2, seg = tid & 3;
        const int t = tile * TILE_T + row;
        float4* drow = (float4*)(&sA[row][seg * 32]);
        if (t < TNODE) {
            const float4* srow = (const float4*)(agg + ((size_t)r * TNODE + t) * C + seg * 32);
            #pragma unroll
            for (int j = 0; j < 8; ++j) drow[j] = srow[j];
        } else {
            #pragma unroll
            for (int j = 0; j < 8; ++j) drow[j] = make_float4(0.f, 0.f, 0.f, 0.f);
        }
    }
    __syncthreads();

    // register-blocked GEMM: thread owns 4 targets x (4 + 4) cols
    const int tg = tid >> 4;   // targets tg*4 .. tg*4+3
    const int cg = tid & 15;   // cols cg*4..+3 and 64+cg*4..+3
    float4 acc0[4], acc1[4];
    #pragma unroll
    for (int i = 0; i < 4; ++i) {
        acc0[i] = make_float4(0.f, 0.f, 0.f, 0.f);
        acc1[i] = make_float4(0.f, 0.f, 0.f, 0.f);
    }
    for (int k4 = 0; k4 < C / 4; ++k4) {
        float4 av[4];
        #pragma unroll
        for (int i = 0; i < 4; ++i)
            av[i] = *(const float4*)&sA[tg * 4 + i][k4 * 4];
        #pragma unroll
        for (int kk = 0; kk < 4; ++kk) {
            const int k = k4 * 4 + kk;
            const uint2 p0 = *(const uint2*)(sW + (size_t)k * C + cg * 4);
            const uint2 p1 = *(const uint2*)(sW + (size_t)k * C + 64 + cg * 4);
            const float2 w01 = unpack_bf2(p0.x), w23 = unpack_bf2(p0.y);
            const float2 w45 = unpack_bf2(p1.x), w67 = unpack_bf2(p1.y);
            #pragma unroll
            for (int i = 0; i < 4; ++i) {
                const float a = ((const float*)&av[i])[kk];
                fma4(acc0[i], a, w01.x, w01.y, w23.x, w23.y);
                fma4(acc1[i], a, w45.x, w45.y, w67.x, w67.y);
            }
        }
    }

    // atomic scatter into out[tgt[t]]
    const int* tr = tgt + (size_t)r * TNODE;
    #pragma unroll
    for (int i = 0; i < 4; ++i) {
        const int t = tile * TILE_T + tg * 4 + i;
        if (t < TNODE) {
            const int node = tr[t];
            float* ob = out + (size_t)node * C + cg * 4;
            unsafeAtomicAdd(ob + 0,      acc0[i].x);
            unsafeAtomicAdd(ob + 1,      acc0[i].y);
            unsafeAtomicAdd(ob + 2,      acc0[i].z);
            unsafeAtomicAdd(ob + 3,      acc0[i].w);
            unsafeAtomicAdd(ob + 64 + 0, acc1[i].x);
            unsafeAtomicAdd(ob + 64 + 1, acc1[i].y);
            unsafeAtomicAdd(ob + 64 + 2, acc1[i].z);
            unsafeAtomicAdd(ob + 64 + 3, acc1[i].w);
        }
    }
}

// ---------------- fallback: round-1 fused kernel (used only if ws too small) ----------------
__device__ __forceinline__ void add4(float4& acc, const float4& b) {
    acc.x += b.x; acc.y += b.y; acc.z += b.z; acc.w += b.w;
}
__global__ __launch_bounds__(256, 1)
void rgcn_fused_kernel(const float* __restrict__ x, const float* __restrict__ w,
                       const int* __restrict__ ptr, const int* __restrict__ idx,
                       const int* __restrict__ tgt, float* __restrict__ out) {
    __shared__ float sW[C * C];
    __shared__ float sAgg[TILE_T][C + 4];
    const int tid = threadIdx.x, tile = blockIdx.x, r = blockIdx.y;
    {
        const float4* src = (const float4*)(w + (size_t)r * C * C);
        float4* dst = (float4*)sW;
        #pragma unroll
        for (int i = 0; i < 16; ++i) dst[tid + i * 256] = src[tid + i * 256];
    }
    {
        const int tl = tid >> 2, g = tid & 3;
        const int t = tile * TILE_T + tl;
        float4 a[8];
        #pragma unroll
        for (int j = 0; j < 8; ++j) a[j] = make_float4(0.f, 0.f, 0.f, 0.f);
        if (t < TNODE) {
            const int* pr = ptr + (size_t)r * (TNODE + 1);
            const int* er = idx + (size_t)r * NEDGE;
            int e = (t == 0) ? 0 : pr[t];
            const int end = (t == TNODE - 1) ? NEDGE : pr[t + 1];
            for (; e < end; ++e) {
                const int s0 = er[e];
                const float4* r0 = (const float4*)(x + (size_t)s0 * C) + g * 8;
                #pragma unroll
                for (int j = 0; j < 8; ++j) add4(a[j], r0[j]);
            }
        }
        float* rowp = &sAgg[tl][g * 32];
        #pragma unroll
        for (int j = 0; j < 8; ++j) ((float4*)rowp)[j] = a[j];
    }
    __syncthreads();
    const int tg = tid >> 4, cg = tid & 15;
    float4 acc0[4], acc1[4];
    #pragma unroll
    for (int i = 0; i < 4; ++i) {
        acc0[i] = make_float4(0.f, 0.f, 0.f, 0.f);
        acc1[i] = make_float4(0.f, 0.f, 0.f, 0.f);
    }
    for (int k4 = 0; k4 < C / 4; ++k4) {
        float4 av[4];
        #pragma unroll
        for (int i = 0; i < 4; ++i) av[i] = *(const float4*)&sAgg[tg * 4 + i][k4 * 4];
        #pragma unroll
        for (int kk = 0; kk < 4; ++kk) {
            const int k = k4 * 4 + kk;
            const float4 w0 = *(const float4*)&sW[k * C + cg * 4];
            const float4 w1 = *(const float4*)&sW[k * C + 64 + cg * 4];
            #pragma unroll
            for (int i = 0; i < 4; ++i) {
                const float a = ((const float*)&av[i])[kk];
                fma4(acc0[i], a, w0.x, w0.y, w0.z, w0.w);
                fma4(acc1[i], a, w1.x, w1.y, w1.z, w1.w);
            }
        }
    }
    const int* tr = tgt + (size_t)r * TNODE;
    #pragma unroll
    for (int i = 0; i < 4; ++i) {
        const int t = tile * TILE_T + tg * 4 + i;
        if (t < TNODE) {
            const int node = tr[t];
            float* ob = out + (size_t)node * C + cg * 4;
            unsafeAtomicAdd(ob + 0, acc0[i].x);  unsafeAtomicAdd(ob + 1, acc0[i].y);
            unsafeAtomicAdd(ob + 2, acc0[i].z);  unsafeAtomicAdd(ob + 3, acc0[i].w);
            unsafeAtomicAdd(ob + 64, acc1[i].x); unsafeAtomicAdd(ob + 65, acc1[i].y);
            unsafeAtomicAdd(ob + 66, acc1[i].z); unsafeAtomicAdd(ob + 67, acc1[i].w);
        }
    }
}

extern "C" void kernel_launch(void* const* d_in, const int* in_sizes, int n_in,
                              void* d_out, int out_size, void* d_ws, size_t ws_size,
                              hipStream_t stream) {
    const float* x   = (const float*)d_in[0];
    const float* w   = (const float*)d_in[1];
    const int*   ptr = (const int*)d_in[2];
    const int*   idx = (const int*)d_in[3];
    const int*   tgt = (const int*)d_in[4];
    float* out = (float*)d_out;

    hipMemsetAsync(out, 0, (size_t)NNODE * C * sizeof(float), stream);

    const size_t XB_BYTES  = (size_t)NNODE * C * sizeof(u16);          // 25,600,000
    const size_t AGG_BYTES = (size_t)NREL * TNODE * C * sizeof(float); // 204,800,000

    if (ws_size >= XB_BYTES + AGG_BYTES) {
        u16*   xb  = (u16*)d_ws;
        float* agg = (float*)((char*)d_ws + XB_BYTES);

        convert_x_kernel<<<2048, 256, 0, stream>>>(x, xb, NNODE * C / 4);

        const int nblk = NREL * TNODE / 4;   // 4 waves/block, 1 wave/target
        gather_kernel<<<nblk, 256, 0, stream>>>(xb, ptr, idx, agg);

        dim3 grid(NTILE, NREL);
        gemm_scatter_kernel<<<grid, 256, 0, stream>>>(agg, w, tgt, out);
    } else {
        dim3 grid(NTILE, NREL);
        rgcn_fused_kernel<<<grid, 256, 0, stream>>>(x, w, ptr, idx, tgt, out);
    }
}

// Round 4
// 519.578 us; speedup vs baseline: 2.5495x; 1.8730x over previous
//
#include <hip/hip_runtime.h>

#define NREL 8
#define NNODE 100000
#define TNODE 50000
#define NEDGE 800000
#define C 128
#define TILE_T 64
#define NTILE ((TNODE + TILE_T - 1) / TILE_T)   // 782
#define NENT (NREL * TNODE)                     // 400000 scatter entries
#define NB_SCAN ((NNODE + 255) / 256)           // 391

typedef unsigned int u32;
typedef unsigned short u16;

__device__ __forceinline__ float bf2f(u16 h) {
    union { u32 u; float f; } c; c.u = ((u32)h) << 16; return c.f;
}
__device__ __forceinline__ u16 f2bf(float f) {
    union { float f; u32 u; } c; c.f = f;
    u32 u = c.u + 0x7FFFu + ((c.u >> 16) & 1u);   // RNE
    return (u16)(u >> 16);
}
__device__ __forceinline__ float2 unpack_bf2(u32 p) {
    union { u32 u; float f; } a, b;
    a.u = p << 16; b.u = p & 0xFFFF0000u;
    return make_float2(a.f, b.f);
}
__device__ __forceinline__ void fma4(float4& acc, float a, float w0, float w1, float w2, float w3) {
    acc.x = fmaf(a, w0, acc.x);
    acc.y = fmaf(a, w1, acc.y);
    acc.z = fmaf(a, w2, acc.z);
    acc.w = fmaf(a, w3, acc.w);
}
__device__ __forceinline__ void add8(float* a, uint4 v) {
    const float2 f0 = unpack_bf2(v.x), f1 = unpack_bf2(v.y);
    const float2 f2 = unpack_bf2(v.z), f3 = unpack_bf2(v.w);
    a[0] += f0.x; a[1] += f0.y; a[2] += f1.x; a[3] += f1.y;
    a[4] += f2.x; a[5] += f2.y; a[6] += f3.x; a[7] += f3.y;
}

// ---------------- kernel 1: x f32 -> bf16 ----------------
__global__ __launch_bounds__(256)
void convert_x_kernel(const float* __restrict__ x, u16* __restrict__ xb, int n4) {
    int i = blockIdx.x * 256 + threadIdx.x;
    const int stride = gridDim.x * 256;
    for (; i < n4; i += stride) {
        const float4 v = ((const float4*)x)[i];
        ushort4 o;
        o.x = f2bf(v.x); o.y = f2bf(v.y); o.z = f2bf(v.z); o.w = f2bf(v.w);
        ((ushort4*)xb)[i] = o;
    }
}

// ---------------- kernel 2: gather-sum, one wave per target, 4 edges in flight ----------------
__global__ __launch_bounds__(256, 6)
void gather_kernel(const u16* __restrict__ xb, const int* __restrict__ ptr,
                   const int* __restrict__ idx, float* __restrict__ P) {
    const int lane = threadIdx.x & 63;
    const int wid  = threadIdx.x >> 6;
    const int g    = blockIdx.x * 4 + wid;       // global (rel,target) id
    const int r    = g / TNODE;
    const int t    = g - r * TNODE;

    const int* pr = ptr + r * (TNODE + 1);
    const int* er = idx + (size_t)r * NEDGE;
    // clip(searchsorted(ptr,e,'right')-1, 0, T-1):
    //   t==0 owns [0, ptr[1]); t==T-1 owns [ptr[T-1], E)
    const int start = (t == 0) ? 0 : pr[t];
    const int end   = (t == TNODE - 1) ? NEDGE : pr[t + 1];

    const int q  = lane >> 4;    // edge slot 0..3
    const int sl = lane & 15;    // 8-col chunk (16B)
    float acc[8];
    #pragma unroll
    for (int j = 0; j < 8; ++j) acc[j] = 0.f;
    const u16* xcol = xb + sl * 8;

    for (int base = start; base < end; base += 64) {
        const int cnt = min(end - base, 64);
        int myi = (lane < cnt) ? er[base + lane] : 0;
        int i = 0;
        for (; i + 8 <= cnt; i += 8) {           // 8 edges/iter, 2 loads in flight/lane
            const int sA = __shfl(myi, i + q);
            const int sB = __shfl(myi, i + 4 + q);
            const uint4 vA = *(const uint4*)(xcol + (size_t)sA * C);
            const uint4 vB = *(const uint4*)(xcol + (size_t)sB * C);
            add8(acc, vA);
            add8(acc, vB);
        }
        if (i + 4 <= cnt) {
            const int sA = __shfl(myi, i + q);
            const uint4 vA = *(const uint4*)(xcol + (size_t)sA * C);
            add8(acc, vA);
            i += 4;
        }
        if (i < cnt) {                           // 1..3 leftover edges
            const int rem = cnt - i;
            const int sA = __shfl(myi, i + ((q < rem) ? q : 0));
            if (q < rem) {
                const uint4 vA = *(const uint4*)(xcol + (size_t)sA * C);
                add8(acc, vA);
            }
        }
    }
    // fold the 4 quarter-waves
    #pragma unroll
    for (int j = 0; j < 8; ++j) {
        acc[j] += __shfl_xor(acc[j], 16);
        acc[j] += __shfl_xor(acc[j], 32);
    }
    if (q == 0) {
        float* dst = P + (size_t)g * C + sl * 8;
        *(float4*)(dst)     = make_float4(acc[0], acc[1], acc[2], acc[3]);
        *(float4*)(dst + 4) = make_float4(acc[4], acc[5], acc[6], acc[7]);
    }
}

// ---------------- inverted-index build ----------------
__global__ __launch_bounds__(256)
void hist_kernel(const int* __restrict__ tgt, int* __restrict__ count) {
    const int g = blockIdx.x * 256 + threadIdx.x;
    if (g < NENT) atomicAdd(&count[tgt[g]], 1);
}

__global__ __launch_bounds__(256)
void scan1_kernel(const int* __restrict__ count, int* __restrict__ bsum) {
    __shared__ int s[256];
    const int tid = threadIdx.x;
    const int i = blockIdx.x * 256 + tid;
    s[tid] = (i < NNODE) ? count[i] : 0;
    __syncthreads();
    for (int st = 128; st > 0; st >>= 1) {
        if (tid < st) s[tid] += s[tid + st];
        __syncthreads();
    }
    if (tid == 0) bsum[blockIdx.x] = s[0];
}

__global__ __launch_bounds__(512)
void scan2_kernel(int* __restrict__ bsum) {   // 1 block, exclusive scan of NB_SCAN partials
    __shared__ int s[512];
    const int tid = threadIdx.x;
    const int v = (tid < NB_SCAN) ? bsum[tid] : 0;
    s[tid] = v;
    __syncthreads();
    for (int st = 1; st < 512; st <<= 1) {
        const int t = (tid >= st) ? s[tid - st] : 0;
        __syncthreads();
        s[tid] += t;
        __syncthreads();
    }
    if (tid < NB_SCAN) bsum[tid] = s[tid] - v;   // exclusive
}

__global__ __launch_bounds__(256)
void scan3_kernel(const int* __restrict__ count, const int* __restrict__ bsum,
                  int* __restrict__ offsets, int* __restrict__ cursor) {
    __shared__ int s[256];
    const int tid = threadIdx.x;
    const int i = blockIdx.x * 256 + tid;
    const int v = (i < NNODE) ? count[i] : 0;
    s[tid] = v;
    __syncthreads();
    for (int st = 1; st < 256; st <<= 1) {
        const int t = (tid >= st) ? s[tid - st] : 0;
        __syncthreads();
        s[tid] += t;
        __syncthreads();
    }
    if (i < NNODE) {
        const int off = bsum[blockIdx.x] + s[tid] - v;   // exclusive prefix
        offsets[i] = off;
        cursor[i]  = off;
    }
}

__global__ __launch_bounds__(256)
void fill_kernel(const int* __restrict__ tgt, int* __restrict__ cursor, int* __restrict__ list) {
    const int g = blockIdx.x * 256 + threadIdx.x;
    if (g < NENT) {
        const int pos = atomicAdd(&cursor[tgt[g]], 1);
        list[pos] = g;
    }
}

// ---------------- kernel 3: tile GEMM, in-place P (agg -> arr), no atomics ----------------
__global__ __launch_bounds__(256, 2)
void gemm_arr_kernel(float* P, const float* __restrict__ w) {
    __shared__ u16   sW[C * C];             // 32 KB, bf16 [k][c]
    __shared__ float sA[TILE_T][C + 4];     // 33.8 KB, f32 agg tile

    const int tid  = threadIdx.x;
    const int tile = blockIdx.x;
    const int r    = blockIdx.y;

    // stage W_r -> bf16 LDS
    {
        const float4* src = (const float4*)(w + (size_t)r * C * C);
        #pragma unroll
        for (int i = 0; i < 16; ++i) {
            const float4 v = src[tid + i * 256];
            ushort4 o;
            o.x = f2bf(v.x); o.y = f2bf(v.y); o.z = f2bf(v.z); o.w = f2bf(v.w);
            ((ushort4*)sW)[tid + i * 256] = o;
        }
    }
    // stage agg tile (f32) — all reads of these rows complete before the barrier
    {
        const int row = tid >> 2, seg = tid & 3;
        const int t = tile * TILE_T + row;
        float4* drow = (float4*)(&sA[row][seg * 32]);
        if (t < TNODE) {
            const float4* srow = (const float4*)(P + ((size_t)r * TNODE + t) * C + seg * 32);
            #pragma unroll
            for (int j = 0; j < 8; ++j) drow[j] = srow[j];
        } else {
            #pragma unroll
            for (int j = 0; j < 8; ++j) drow[j] = make_float4(0.f, 0.f, 0.f, 0.f);
        }
    }
    __syncthreads();

    // register-blocked GEMM: thread owns 4 targets x (4 + 4) cols
    const int tg = tid >> 4;
    const int cg = tid & 15;
    float4 acc0[4], acc1[4];
    #pragma unroll
    for (int i = 0; i < 4; ++i) {
        acc0[i] = make_float4(0.f, 0.f, 0.f, 0.f);
        acc1[i] = make_float4(0.f, 0.f, 0.f, 0.f);
    }
    for (int k4 = 0; k4 < C / 4; ++k4) {
        float4 av[4];
        #pragma unroll
        for (int i = 0; i < 4; ++i)
            av[i] = *(const float4*)&sA[tg * 4 + i][k4 * 4];
        #pragma unroll
        for (int kk = 0; kk < 4; ++kk) {
            const int k = k4 * 4 + kk;
            const uint2 p0 = *(const uint2*)(sW + (size_t)k * C + cg * 4);
            const uint2 p1 = *(const uint2*)(sW + (size_t)k * C + 64 + cg * 4);
            const float2 w01 = unpack_bf2(p0.x), w23 = unpack_bf2(p0.y);
            const float2 w45 = unpack_bf2(p1.x), w67 = unpack_bf2(p1.y);
            #pragma unroll
            for (int i = 0; i < 4; ++i) {
                const float a = ((const float*)&av[i])[kk];
                fma4(acc0[i], a, w01.x, w01.y, w23.x, w23.y);
                fma4(acc1[i], a, w45.x, w45.y, w67.x, w67.y);
            }
        }
    }

    // plain streaming store back into P (in place)
    #pragma unroll
    for (int i = 0; i < 4; ++i) {
        const int t = tile * TILE_T + tg * 4 + i;
        if (t < TNODE) {
            float4* ob = (float4*)(P + ((size_t)r * TNODE + t) * C);
            ob[cg]      = acc0[i];
            ob[16 + cg] = acc1[i];
        }
    }
}

// ---------------- kernel 4: per-node gather of arr rows (no atomics) ----------------
__global__ __launch_bounds__(256)
void out_gather_kernel(const float* __restrict__ P, const int* __restrict__ offsets,
                       const int* __restrict__ count, const int* __restrict__ list,
                       float* __restrict__ out) {
    const int lane = threadIdx.x & 63;
    const int n = blockIdx.x * 4 + (threadIdx.x >> 6);
    if (n >= NNODE) return;
    const int st = offsets[n];
    const int en = st + count[n];
    float2 a0 = make_float2(0.f, 0.f), a1 = make_float2(0.f, 0.f);
    int i = st;
    for (; i + 2 <= en; i += 2) {
        const int g0 = list[i], g1 = list[i + 1];
        const float2 v0 = ((const float2*)(P + (size_t)g0 * C))[lane];
        const float2 v1 = ((const float2*)(P + (size_t)g1 * C))[lane];
        a0.x += v0.x; a0.y += v0.y;
        a1.x += v1.x; a1.y += v1.y;
    }
    if (i < en) {
        const float2 v0 = ((const float2*)(P + (size_t)list[i] * C))[lane];
        a0.x += v0.x; a0.y += v0.y;
    }
    a0.x += a1.x; a0.y += a1.y;
    ((float2*)(out + (size_t)n * C))[lane] = a0;
}

// ---------------- fallback: round-1 fused kernel (used only if ws too small) ----------------
__device__ __forceinline__ void add4(float4& acc, const float4& b) {
    acc.x += b.x; acc.y += b.y; acc.z += b.z; acc.w += b.w;
}
__global__ __launch_bounds__(256, 1)
void rgcn_fused_kernel(const float* __restrict__ x, const float* __restrict__ w,
                       const int* __restrict__ ptr, const int* __restrict__ idx,
                       const int* __restrict__ tgt, float* __restrict__ out) {
    __shared__ float sW[C * C];
    __shared__ float sAgg[TILE_T][C + 4];
    const int tid = threadIdx.x, tile = blockIdx.x, r = blockIdx.y;
    {
        const float4* src = (const float4*)(w + (size_t)r * C * C);
        float4* dst = (float4*)sW;
        #pragma unroll
        for (int i = 0; i < 16; ++i) dst[tid + i * 256] = src[tid + i * 256];
    }
    {
        const int tl = tid >> 2, g = tid & 3;
        const int t = tile * TILE_T + tl;
        float4 a[8];
        #pragma unroll
        for (int j = 0; j < 8; ++j) a[j] = make_float4(0.f, 0.f, 0.f, 0.f);
        if (t < TNODE) {
            const int* pr = ptr + (size_t)r * (TNODE + 1);
            const int* er = idx + (size_t)r * NEDGE;
            int e = (t == 0) ? 0 : pr[t];
            const int end = (t == TNODE - 1) ? NEDGE : pr[t + 1];
            for (; e < end; ++e) {
                const int s0 = er[e];
                const float4* r0 = (const float4*)(x + (size_t)s0 * C) + g * 8;
                #pragma unroll
                for (int j = 0; j < 8; ++j) add4(a[j], r0[j]);
            }
        }
        float* rowp = &sAgg[tl][g * 32];
        #pragma unroll
        for (int j = 0; j < 8; ++j) ((float4*)rowp)[j] = a[j];
    }
    __syncthreads();
    const int tg = tid >> 4, cg = tid & 15;
    float4 acc0[4], acc1[4];
    #pragma unroll
    for (int i = 0; i < 4; ++i) {
        acc0[i] = make_float4(0.f, 0.f, 0.f, 0.f);
        acc1[i] = make_float4(0.f, 0.f, 0.f, 0.f);
    }
    for (int k4 = 0; k4 < C / 4; ++k4) {
        float4 av[4];
        #pragma unroll
        for (int i = 0; i < 4; ++i) av[i] = *(const float4*)&sAgg[tg * 4 + i][k4 * 4];
        #pragma unroll
        for (int kk = 0; kk < 4; ++kk) {
            const int k = k4 * 4 + kk;
            const float4 w0 = *(const float4*)&sW[k * C + cg * 4];
            const float4 w1 = *(const float4*)&sW[k * C + 64 + cg * 4];
            #pragma unroll
            for (int i = 0; i < 4; ++i) {
                const float a = ((const float*)&av[i])[kk];
                fma4(acc0[i], a, w0.x, w0.y, w0.z, w0.w);
                fma4(acc1[i], a, w1.x, w1.y, w1.z, w1.w);
            }
        }
    }
    const int* tr = tgt + (size_t)r * TNODE;
    #pragma unroll
    for (int i = 0; i < 4; ++i) {
        const int t = tile * TILE_T + tg * 4 + i;
        if (t < TNODE) {
            const int node = tr[t];
            float* ob = out + (size_t)node * C + cg * 4;
            unsafeAtomicAdd(ob + 0, acc0[i].x);  unsafeAtomicAdd(ob + 1, acc0[i].y);
            unsafeAtomicAdd(ob + 2, acc0[i].z);  unsafeAtomicAdd(ob + 3, acc0[i].w);
            unsafeAtomicAdd(ob + 64, acc1[i].x); unsafeAtomicAdd(ob + 65, acc1[i].y);
            unsafeAtomicAdd(ob + 66, acc1[i].z); unsafeAtomicAdd(ob + 67, acc1[i].w);
        }
    }
}

extern "C" void kernel_launch(void* const* d_in, const int* in_sizes, int n_in,
                              void* d_out, int out_size, void* d_ws, size_t ws_size,
                              hipStream_t stream) {
    const float* x   = (const float*)d_in[0];
    const float* w   = (const float*)d_in[1];
    const int*   ptr = (const int*)d_in[2];
    const int*   idx = (const int*)d_in[3];
    const int*   tgt = (const int*)d_in[4];
    float* out = (float*)d_out;

    const size_t P_BYTES  = (size_t)NENT * C * sizeof(float);   // 204,800,000
    const size_t XB_BYTES = (size_t)NNODE * C * sizeof(u16);    //  25,600,000

    if (ws_size >= P_BYTES + XB_BYTES) {
        float* P  = (float*)d_ws;
        char*  xbase = (char*)d_ws + P_BYTES;        // 25.6 MB region: xb, later index arrays
        u16*   xb = (u16*)xbase;
        int* count   = (int*)xbase;                  // reuses xb space AFTER gather
        int* offsets = (int*)(xbase + 400000);
        int* cursor  = (int*)(xbase + 800000);
        int* bsum    = (int*)(xbase + 1200000);
        int* list    = (int*)(xbase + 1300000);      // 1.6 MB, ends < 3 MB

        convert_x_kernel<<<2048, 256, 0, stream>>>(x, xb, NNODE * C / 4);
        gather_kernel<<<NENT / 4, 256, 0, stream>>>(xb, ptr, idx, P);

        // xb is dead from here on; build inverted index in its space
        hipMemsetAsync(count, 0, NNODE * sizeof(int), stream);
        hist_kernel<<<(NENT + 255) / 256, 256, 0, stream>>>(tgt, count);
        scan1_kernel<<<NB_SCAN, 256, 0, stream>>>(count, bsum);
        scan2_kernel<<<1, 512, 0, stream>>>(bsum);
        scan3_kernel<<<NB_SCAN, 256, 0, stream>>>(count, bsum, offsets, cursor);
        fill_kernel<<<(NENT + 255) / 256, 256, 0, stream>>>(tgt, cursor, list);

        dim3 grid(NTILE, NREL);
        gemm_arr_kernel<<<grid, 256, 0, stream>>>(P, w);

        out_gather_kernel<<<(NNODE + 3) / 4, 256, 0, stream>>>(P, offsets, count, list, out);
    } else {
        hipMemsetAsync(out, 0, (size_t)NNODE * C * sizeof(float), stream);
        dim3 grid(NTILE, NREL);
        rgcn_fused_kernel<<<grid, 256, 0, stream>>>(x, w, ptr, idx, tgt, out);
    }
}

// Round 5
// 356.354 us; speedup vs baseline: 3.7172x; 1.4580x over previous
//
#include <hip/hip_runtime.h>

#define NREL 8
#define NNODE 100000
#define TNODE 50000
#define NEDGE 800000
#define C 128
#define TILE_T 64
#define NTILE ((TNODE + TILE_T - 1) / TILE_T)   // 782
#define NENT (NREL * TNODE)                     // 400000 scatter entries
#define NB_SCAN ((NNODE + 255) / 256)           // 391

typedef unsigned int u32;
typedef unsigned short u16;
typedef __attribute__((ext_vector_type(8))) short bf16x8;
typedef __attribute__((ext_vector_type(4))) float f32x4;

__device__ __forceinline__ float bf2f(u16 h) {
    union { u32 u; float f; } c; c.u = ((u32)h) << 16; return c.f;
}
__device__ __forceinline__ u16 f2bf(float f) {
    union { float f; u32 u; } c; c.f = f;
    u32 u = c.u + 0x7FFFu + ((c.u >> 16) & 1u);   // RNE
    return (u16)(u >> 16);
}
__device__ __forceinline__ u32 pack2(float a, float b) {
    return (u32)f2bf(a) | ((u32)f2bf(b) << 16);
}
__device__ __forceinline__ float2 unpack_bf2(u32 p) {
    union { u32 u; float f; } a, b;
    a.u = p << 16; b.u = p & 0xFFFF0000u;
    return make_float2(a.f, b.f);
}
__device__ __forceinline__ void fma4(float4& acc, float a, float w0, float w1, float w2, float w3) {
    acc.x = fmaf(a, w0, acc.x);
    acc.y = fmaf(a, w1, acc.y);
    acc.z = fmaf(a, w2, acc.z);
    acc.w = fmaf(a, w3, acc.w);
}
__device__ __forceinline__ void add8(float* a, uint4 v) {
    const float2 f0 = unpack_bf2(v.x), f1 = unpack_bf2(v.y);
    const float2 f2 = unpack_bf2(v.z), f3 = unpack_bf2(v.w);
    a[0] += f0.x; a[1] += f0.y; a[2] += f1.x; a[3] += f1.y;
    a[4] += f2.x; a[5] += f2.y; a[6] += f3.x; a[7] += f3.y;
}

// ---------------- kernel 1a: x f32 -> bf16 ----------------
__global__ __launch_bounds__(256)
void convert_x_kernel(const float* __restrict__ x, u16* __restrict__ xb, int n4) {
    int i = blockIdx.x * 256 + threadIdx.x;
    const int stride = gridDim.x * 256;
    for (; i < n4; i += stride) {
        const float4 v = ((const float4*)x)[i];
        ushort4 o;
        o.x = f2bf(v.x); o.y = f2bf(v.y); o.z = f2bf(v.z); o.w = f2bf(v.w);
        ((ushort4*)xb)[i] = o;
    }
}

// ---------------- kernel 1b: W f32 [r][k][c] -> bf16 W^T [r][c][k] ----------------
__global__ __launch_bounds__(256)
void convert_w_kernel(const float* __restrict__ w, u16* __restrict__ wtb) {
    const int o = blockIdx.x * 256 + threadIdx.x;   // enumerates (r, c, k), k inner
    if (o < NREL * C * C) {
        const int r = o >> 14, rem = o & 16383, cc = rem >> 7, k = rem & 127;
        wtb[o] = f2bf(w[(r << 14) + k * C + cc]);
    }
}

// ---------------- kernel 2: gather-sum, one wave per target, bf16 out ----------------
__global__ __launch_bounds__(256, 6)
void gather_kernel(const u16* __restrict__ xb, const int* __restrict__ ptr,
                   const int* __restrict__ idx, u16* __restrict__ P) {
    const int lane = threadIdx.x & 63;
    const int wid  = threadIdx.x >> 6;
    const int g    = blockIdx.x * 4 + wid;       // global (rel,target) id
    const int r    = g / TNODE;
    const int t    = g - r * TNODE;

    const int* pr = ptr + r * (TNODE + 1);
    const int* er = idx + (size_t)r * NEDGE;
    // clip(searchsorted(ptr,e,'right')-1, 0, T-1):
    //   t==0 owns [0, ptr[1]); t==T-1 owns [ptr[T-1], E)
    const int start = (t == 0) ? 0 : pr[t];
    const int end   = (t == TNODE - 1) ? NEDGE : pr[t + 1];

    const int q  = lane >> 4;    // edge slot 0..3
    const int sl = lane & 15;    // 8-col chunk (16B)
    float accA[8], accB[8];
    #pragma unroll
    for (int j = 0; j < 8; ++j) { accA[j] = 0.f; accB[j] = 0.f; }
    const u16* xcol = xb + sl * 8;

    for (int base = start; base < end; base += 64) {
        const int cnt = min(end - base, 64);
        int myi = (lane < cnt) ? er[base + lane] : 0;
        int i = 0;
        for (; i + 8 <= cnt; i += 8) {           // 8 edges/iter, 2 loads in flight/lane
            const int sA = __shfl(myi, i + q);
            const int sB = __shfl(myi, i + 4 + q);
            const uint4 vA = *(const uint4*)(xcol + (size_t)sA * C);
            const uint4 vB = *(const uint4*)(xcol + (size_t)sB * C);
            add8(accA, vA);
            add8(accB, vB);
        }
        if (i + 4 <= cnt) {
            const int sA = __shfl(myi, i + q);
            const uint4 vA = *(const uint4*)(xcol + (size_t)sA * C);
            add8(accA, vA);
            i += 4;
        }
        if (i < cnt) {                           // 1..3 leftover edges
            const int rem = cnt - i;
            const int sA = __shfl(myi, i + ((q < rem) ? q : 0));
            if (q < rem) {
                const uint4 vA = *(const uint4*)(xcol + (size_t)sA * C);
                add8(accA, vA);
            }
        }
    }
    #pragma unroll
    for (int j = 0; j < 8; ++j) {
        accA[j] += accB[j];
        accA[j] += __shfl_xor(accA[j], 16);
        accA[j] += __shfl_xor(accA[j], 32);
    }
    if (q == 0) {
        uint4 o;
        o.x = pack2(accA[0], accA[1]);
        o.y = pack2(accA[2], accA[3]);
        o.z = pack2(accA[4], accA[5]);
        o.w = pack2(accA[6], accA[7]);
        *(uint4*)(P + (size_t)g * C + sl * 8) = o;
    }
}

// ---------------- inverted-index build ----------------
__global__ __launch_bounds__(256)
void hist_kernel(const int* __restrict__ tgt, int* __restrict__ count) {
    const int g = blockIdx.x * 256 + threadIdx.x;
    if (g < NENT) atomicAdd(&count[tgt[g]], 1);
}

__global__ __launch_bounds__(256)
void scan1_kernel(const int* __restrict__ count, int* __restrict__ bsum) {
    __shared__ int s[256];
    const int tid = threadIdx.x;
    const int i = blockIdx.x * 256 + tid;
    s[tid] = (i < NNODE) ? count[i] : 0;
    __syncthreads();
    for (int st = 128; st > 0; st >>= 1) {
        if (tid < st) s[tid] += s[tid + st];
        __syncthreads();
    }
    if (tid == 0) bsum[blockIdx.x] = s[0];
}

__global__ __launch_bounds__(512)
void scan2_kernel(int* __restrict__ bsum) {   // 1 block, exclusive scan of NB_SCAN partials
    __shared__ int s[512];
    const int tid = threadIdx.x;
    const int v = (tid < NB_SCAN) ? bsum[tid] : 0;
    s[tid] = v;
    __syncthreads();
    for (int st = 1; st < 512; st <<= 1) {
        const int t = (tid >= st) ? s[tid - st] : 0;
        __syncthreads();
        s[tid] += t;
        __syncthreads();
    }
    if (tid < NB_SCAN) bsum[tid] = s[tid] - v;   // exclusive
}

__global__ __launch_bounds__(256)
void scan3_kernel(const int* __restrict__ count, const int* __restrict__ bsum,
                  int* __restrict__ offsets, int* __restrict__ cursor) {
    __shared__ int s[256];
    const int tid = threadIdx.x;
    const int i = blockIdx.x * 256 + tid;
    const int v = (i < NNODE) ? count[i] : 0;
    s[tid] = v;
    __syncthreads();
    for (int st = 1; st < 256; st <<= 1) {
        const int t = (tid >= st) ? s[tid - st] : 0;
        __syncthreads();
        s[tid] += t;
        __syncthreads();
    }
    if (i < NNODE) {
        const int off = bsum[blockIdx.x] + s[tid] - v;   // exclusive prefix
        offsets[i] = off;
        cursor[i]  = off;
    }
}

__global__ __launch_bounds__(256)
void fill_kernel(const int* __restrict__ tgt, int* __restrict__ cursor, int* __restrict__ list) {
    const int g = blockIdx.x * 256 + threadIdx.x;
    if (g < NENT) {
        const int pos = atomicAdd(&cursor[tgt[g]], 1);
        list[pos] = g;
    }
}

// ---------------- kernel 3: MFMA bf16 GEMM, in-place P ----------------
// A = P tile [64][128] bf16 (row-major), B^T = wtb [col][k] bf16.
// LDS rows padded to 136 bf16 (272 B): per-bank dword load is balanced for ds_read_b128.
__global__ __launch_bounds__(256, 3)
void gemm_mfma_kernel(u16* P, const u16* __restrict__ wtb) {
    __shared__ u16 sB[C * 136];        // 34816 B: W^T [col][k+pad]
    __shared__ u16 sA[TILE_T * 136];   // 17408 B: A tile / output tile

    const int tid  = threadIdx.x;
    const int tile = blockIdx.x;
    const int r    = blockIdx.y;

    // stage W^T (bf16, already transposed in global)
    {
        const uint4* src = (const uint4*)(wtb + (size_t)r * C * C);
        #pragma unroll
        for (int i = 0; i < 8; ++i) {
            const int f = tid + i * 256;        // 16B-unit index, 2048 units
            const int col = f >> 4, unit = f & 15;
            *(uint4*)(sB + col * 136 + unit * 8) = src[f];
        }
    }
    // stage A tile from P
    {
        #pragma unroll
        for (int i = 0; i < 4; ++i) {
            const int f = tid + i * 256;        // 1024 units
            const int row = f >> 4, unit = f & 15;
            const int t = tile * TILE_T + row;
            uint4 v = make_uint4(0u, 0u, 0u, 0u);
            if (t < TNODE)
                v = *(const uint4*)(P + ((size_t)r * TNODE + t) * C + unit * 8);
            *(uint4*)(sA + row * 136 + unit * 8) = v;
        }
    }
    __syncthreads();

    const int lane = tid & 63;
    const int wr   = (tid >> 6) * 16;   // wave's 16-row block
    const int fr   = lane & 15;
    const int fq   = lane >> 4;

    f32x4 acc[8];
    #pragma unroll
    for (int cf = 0; cf < 8; ++cf) acc[cf] = (f32x4){0.f, 0.f, 0.f, 0.f};

    #pragma unroll
    for (int ks = 0; ks < 4; ++ks) {
        const bf16x8 a = *(const bf16x8*)(sA + (wr + fr) * 136 + ks * 32 + fq * 8);
        #pragma unroll
        for (int cf = 0; cf < 8; ++cf) {
            const bf16x8 b = *(const bf16x8*)(sB + (cf * 16 + fr) * 136 + ks * 32 + fq * 8);
            acc[cf] = __builtin_amdgcn_mfma_f32_16x16x32_bf16(a, b, acc[cf], 0, 0, 0);
        }
    }

    // D -> sA as bf16 (wave-local rows only; in-wave ordering suffices)
    #pragma unroll
    for (int cf = 0; cf < 8; ++cf) {
        #pragma unroll
        for (int j = 0; j < 4; ++j) {
            const int row = wr + fq * 4 + j;        // C/D: col=lane&15, row=(lane>>4)*4+reg
            sA[row * 136 + cf * 16 + fr] = f2bf(acc[cf][j]);
        }
    }
    __syncthreads();

    // coalesced store back into P (in place)
    #pragma unroll
    for (int i = 0; i < 4; ++i) {
        const int f = tid + i * 256;
        const int row = f >> 4, unit = f & 15;
        const int t = tile * TILE_T + row;
        if (t < TNODE)
            *(uint4*)(P + ((size_t)r * TNODE + t) * C + unit * 8) =
                *(const uint4*)(sA + row * 136 + unit * 8);
    }
}

// ---------------- kernel 4: per-node gather of bf16 arr rows (no atomics) ----------------
__global__ __launch_bounds__(256)
void out_gather_kernel(const u16* __restrict__ P, const int* __restrict__ offsets,
                       const int* __restrict__ count, const int* __restrict__ list,
                       float* __restrict__ out) {
    const int lane = threadIdx.x & 63;
    const int n = blockIdx.x * 4 + (threadIdx.x >> 6);
    if (n >= NNODE) return;
    const int st = offsets[n];
    const int en = st + count[n];
    float2 a0 = make_float2(0.f, 0.f), a1 = make_float2(0.f, 0.f);
    int i = st;
    for (; i + 2 <= en; i += 2) {
        const u32 v0 = ((const u32*)(P + (size_t)list[i] * C))[lane];
        const u32 v1 = ((const u32*)(P + (size_t)list[i + 1] * C))[lane];
        const float2 f0 = unpack_bf2(v0), f1 = unpack_bf2(v1);
        a0.x += f0.x; a0.y += f0.y;
        a1.x += f1.x; a1.y += f1.y;
    }
    if (i < en) {
        const float2 f0 = unpack_bf2(((const u32*)(P + (size_t)list[i] * C))[lane]);
        a0.x += f0.x; a0.y += f0.y;
    }
    a0.x += a1.x; a0.y += a1.y;
    ((float2*)(out + (size_t)n * C))[lane] = a0;
}

// ---------------- fallback: round-1 fused kernel (used only if ws too small) ----------------
__device__ __forceinline__ void add4(float4& acc, const float4& b) {
    acc.x += b.x; acc.y += b.y; acc.z += b.z; acc.w += b.w;
}
__global__ __launch_bounds__(256, 1)
void rgcn_fused_kernel(const float* __restrict__ x, const float* __restrict__ w,
                       const int* __restrict__ ptr, const int* __restrict__ idx,
                       const int* __restrict__ tgt, float* __restrict__ out) {
    __shared__ float sW[C * C];
    __shared__ float sAgg[TILE_T][C + 4];
    const int tid = threadIdx.x, tile = blockIdx.x, r = blockIdx.y;
    {
        const float4* src = (const float4*)(w + (size_t)r * C * C);
        float4* dst = (float4*)sW;
        #pragma unroll
        for (int i = 0; i < 16; ++i) dst[tid + i * 256] = src[tid + i * 256];
    }
    {
        const int tl = tid >> 2, g = tid & 3;
        const int t = tile * TILE_T + tl;
        float4 a[8];
        #pragma unroll
        for (int j = 0; j < 8; ++j) a[j] = make_float4(0.f, 0.f, 0.f, 0.f);
        if (t < TNODE) {
            const int* pr = ptr + (size_t)r * (TNODE + 1);
            const int* er = idx + (size_t)r * NEDGE;
            int e = (t == 0) ? 0 : pr[t];
            const int end = (t == TNODE - 1) ? NEDGE : pr[t + 1];
            for (; e < end; ++e) {
                const int s0 = er[e];
                const float4* r0 = (const float4*)(x + (size_t)s0 * C) + g * 8;
                #pragma unroll
                for (int j = 0; j < 8; ++j) add4(a[j], r0[j]);
            }
        }
        float* rowp = &sAgg[tl][g * 32];
        #pragma unroll
        for (int j = 0; j < 8; ++j) ((float4*)rowp)[j] = a[j];
    }
    __syncthreads();
    const int tg = tid >> 4, cg = tid & 15;
    float4 acc0[4], acc1[4];
    #pragma unroll
    for (int i = 0; i < 4; ++i) {
        acc0[i] = make_float4(0.f, 0.f, 0.f, 0.f);
        acc1[i] = make_float4(0.f, 0.f, 0.f, 0.f);
    }
    for (int k4 = 0; k4 < C / 4; ++k4) {
        float4 av[4];
        #pragma unroll
        for (int i = 0; i < 4; ++i) av[i] = *(const float4*)&sAgg[tg * 4 + i][k4 * 4];
        #pragma unroll
        for (int kk = 0; kk < 4; ++kk) {
            const int k = k4 * 4 + kk;
            const float4 w0 = *(const float4*)&sW[k * C + cg * 4];
            const float4 w1 = *(const float4*)&sW[k * C + 64 + cg * 4];
            #pragma unroll
            for (int i = 0; i < 4; ++i) {
                const float a = ((const float*)&av[i])[kk];
                fma4(acc0[i], a, w0.x, w0.y, w0.z, w0.w);
                fma4(acc1[i], a, w1.x, w1.y, w1.z, w1.w);
            }
        }
    }
    const int* tr = tgt + (size_t)r * TNODE;
    #pragma unroll
    for (int i = 0; i < 4; ++i) {
        const int t = tile * TILE_T + tg * 4 + i;
        if (t < TNODE) {
            const int node = tr[t];
            float* ob = out + (size_t)node * C + cg * 4;
            unsafeAtomicAdd(ob + 0, acc0[i].x);  unsafeAtomicAdd(ob + 1, acc0[i].y);
            unsafeAtomicAdd(ob + 2, acc0[i].z);  unsafeAtomicAdd(ob + 3, acc0[i].w);
            unsafeAtomicAdd(ob + 64, acc1[i].x); unsafeAtomicAdd(ob + 65, acc1[i].y);
            unsafeAtomicAdd(ob + 66, acc1[i].z); unsafeAtomicAdd(ob + 67, acc1[i].w);
        }
    }
}

extern "C" void kernel_launch(void* const* d_in, const int* in_sizes, int n_in,
                              void* d_out, int out_size, void* d_ws, size_t ws_size,
                              hipStream_t stream) {
    const float* x   = (const float*)d_in[0];
    const float* w   = (const float*)d_in[1];
    const int*   ptr = (const int*)d_in[2];
    const int*   idx = (const int*)d_in[3];
    const int*   tgt = (const int*)d_in[4];
    float* out = (float*)d_out;

    // workspace layout (all offsets 16B-aligned)
    const size_t P_OFF    = 0;                     // 400000*128*2 = 102,400,000
    const size_t XB_OFF   = 104000000;             // 25,600,000
    const size_t WTB_OFF  = 130000000;             //    262,144
    const size_t CNT_OFF  = 131000000;             //    400,000
    const size_t OFFS_OFF = 131500000;
    const size_t CUR_OFF  = 132000000;
    const size_t BSUM_OFF = 132500000;
    const size_t LIST_OFF = 133000000;             //  1,600,000 -> ends 134.6 MB
    const size_t WS_NEED  = 135000000;

    if (ws_size >= WS_NEED) {
        char* base = (char*)d_ws;
        u16*   P       = (u16*)(base + P_OFF);
        u16*   xb      = (u16*)(base + XB_OFF);
        u16*   wtb     = (u16*)(base + WTB_OFF);
        int*   count   = (int*)(base + CNT_OFF);
        int*   offsets = (int*)(base + OFFS_OFF);
        int*   cursor  = (int*)(base + CUR_OFF);
        int*   bsum    = (int*)(base + BSUM_OFF);
        int*   list    = (int*)(base + LIST_OFF);

        convert_x_kernel<<<2048, 256, 0, stream>>>(x, xb, NNODE * C / 4);
        convert_w_kernel<<<(NREL * C * C + 255) / 256, 256, 0, stream>>>(w, wtb);

        gather_kernel<<<NENT / 4, 256, 0, stream>>>(xb, ptr, idx, P);

        hipMemsetAsync(count, 0, NNODE * sizeof(int), stream);
        hist_kernel<<<(NENT + 255) / 256, 256, 0, stream>>>(tgt, count);
        scan1_kernel<<<NB_SCAN, 256, 0, stream>>>(count, bsum);
        scan2_kernel<<<1, 512, 0, stream>>>(bsum);
        scan3_kernel<<<NB_SCAN, 256, 0, stream>>>(count, bsum, offsets, cursor);
        fill_kernel<<<(NENT + 255) / 256, 256, 0, stream>>>(tgt, cursor, list);

        dim3 grid(NTILE, NREL);
        gemm_mfma_kernel<<<grid, 256, 0, stream>>>(P, wtb);

        out_gather_kernel<<<(NNODE + 3) / 4, 256, 0, stream>>>(P, offsets, count, list, out);
    } else {
        hipMemsetAsync(out, 0, (size_t)NNODE * C * sizeof(float), stream);
        dim3 grid(NTILE, NREL);
        rgcn_fused_kernel<<<grid, 256, 0, stream>>>(x, w, ptr, idx, tgt, out);
    }
}

// Round 6
// 351.496 us; speedup vs baseline: 3.7686x; 1.0138x over previous
//
#include <hip/hip_runtime.h>

#define NREL 8
#define NNODE 100000
#define TNODE 50000
#define NEDGE 800000
#define C 128
#define TILE_T 64
#define NTILE ((TNODE + TILE_T - 1) / TILE_T)   // 782
#define NENT (NREL * TNODE)                     // 400000 scatter entries
#define NB_SCAN ((NNODE + 255) / 256)           // 391

typedef unsigned int u32;
typedef unsigned short u16;
typedef __attribute__((ext_vector_type(8))) short bf16x8;
typedef __attribute__((ext_vector_type(4))) float f32x4;
typedef __attribute__((ext_vector_type(2))) float f32x2;

__device__ __forceinline__ float bf2f(u16 h) {
    union { u32 u; float f; } c; c.u = ((u32)h) << 16; return c.f;
}
__device__ __forceinline__ u16 f2bf(float f) {
    union { float f; u32 u; } c; c.f = f;
    u32 u = c.u + 0x7FFFu + ((c.u >> 16) & 1u);   // RNE
    return (u16)(u >> 16);
}
__device__ __forceinline__ u32 pack2(float a, float b) {
    return (u32)f2bf(a) | ((u32)f2bf(b) << 16);
}
__device__ __forceinline__ float2 unpack_bf2(u32 p) {
    union { u32 u; float f; } a, b;
    a.u = p << 16; b.u = p & 0xFFFF0000u;
    return make_float2(a.f, b.f);
}
__device__ __forceinline__ f32x2 bits2(u32 p) {
    union { u32 u[2]; f32x2 f; } c;
    c.u[0] = p << 16; c.u[1] = p & 0xFFFF0000u;
    return c.f;
}
__device__ __forceinline__ void addp(f32x2* a, uint4 v) {   // 8 bf16 cols -> 4 pk-adds
    a[0] += bits2(v.x); a[1] += bits2(v.y);
    a[2] += bits2(v.z); a[3] += bits2(v.w);
}
__device__ __forceinline__ void fma4(float4& acc, float a, float w0, float w1, float w2, float w3) {
    acc.x = fmaf(a, w0, acc.x);
    acc.y = fmaf(a, w1, acc.y);
    acc.z = fmaf(a, w2, acc.z);
    acc.w = fmaf(a, w3, acc.w);
}

// ---------------- kernel 1a: x f32 -> bf16 ----------------
__global__ __launch_bounds__(256)
void convert_x_kernel(const float* __restrict__ x, u16* __restrict__ xb, int n4) {
    int i = blockIdx.x * 256 + threadIdx.x;
    const int stride = gridDim.x * 256;
    for (; i < n4; i += stride) {
        const float4 v = ((const float4*)x)[i];
        ushort4 o;
        o.x = f2bf(v.x); o.y = f2bf(v.y); o.z = f2bf(v.z); o.w = f2bf(v.w);
        ((ushort4*)xb)[i] = o;
    }
}

// ---------------- kernel 1b: W f32 [r][k][c] -> bf16 W^T [r][c][k] ----------------
__global__ __launch_bounds__(256)
void convert_w_kernel(const float* __restrict__ w, u16* __restrict__ wtb) {
    const int o = blockIdx.x * 256 + threadIdx.x;   // enumerates (r, c, k), k inner
    if (o < NREL * C * C) {
        const int r = o >> 14, rem = o & 16383, cc = rem >> 7, k = rem & 127;
        wtb[o] = f2bf(w[(r << 14) + k * C + cc]);
    }
}

// ---------------- inverted-index build ----------------
__global__ __launch_bounds__(256)
void hist_kernel(const int* __restrict__ tgt, int* __restrict__ count) {
    const int g = blockIdx.x * 256 + threadIdx.x;
    if (g < NENT) atomicAdd(&count[tgt[g]], 1);
}

__global__ __launch_bounds__(256)
void scan1_kernel(const int* __restrict__ count, int* __restrict__ bsum) {
    __shared__ int s[256];
    const int tid = threadIdx.x;
    const int i = blockIdx.x * 256 + tid;
    s[tid] = (i < NNODE) ? count[i] : 0;
    __syncthreads();
    for (int st = 128; st > 0; st >>= 1) {
        if (tid < st) s[tid] += s[tid + st];
        __syncthreads();
    }
    if (tid == 0) bsum[blockIdx.x] = s[0];
}

__global__ __launch_bounds__(512)
void scan2_kernel(int* __restrict__ bsum) {   // 1 block, exclusive scan of NB_SCAN partials
    __shared__ int s[512];
    const int tid = threadIdx.x;
    const int v = (tid < NB_SCAN) ? bsum[tid] : 0;
    s[tid] = v;
    __syncthreads();
    for (int st = 1; st < 512; st <<= 1) {
        const int t = (tid >= st) ? s[tid - st] : 0;
        __syncthreads();
        s[tid] += t;
        __syncthreads();
    }
    if (tid < NB_SCAN) bsum[tid] = s[tid] - v;   // exclusive
}

__global__ __launch_bounds__(256)
void scan3_kernel(const int* __restrict__ count, const int* __restrict__ bsum,
                  int* __restrict__ offsets, int* __restrict__ cursor) {
    __shared__ int s[256];
    const int tid = threadIdx.x;
    const int i = blockIdx.x * 256 + tid;
    const int v = (i < NNODE) ? count[i] : 0;
    s[tid] = v;
    __syncthreads();
    for (int st = 1; st < 256; st <<= 1) {
        const int t = (tid >= st) ? s[tid - st] : 0;
        __syncthreads();
        s[tid] += t;
        __syncthreads();
    }
    if (i < NNODE) {
        const int off = bsum[blockIdx.x] + s[tid] - v;   // exclusive prefix
        offsets[i] = off;
        cursor[i]  = off;
    }
}

__global__ __launch_bounds__(256)
void fill_kernel(const int* __restrict__ tgt, int* __restrict__ cursor, int* __restrict__ list) {
    const int g = blockIdx.x * 256 + threadIdx.x;
    if (g < NENT) {
        const int pos = atomicAdd(&cursor[tgt[g]], 1);
        list[pos] = g;
    }
}

// ---------------- kernel 2: FUSED gather-sum + MFMA GEMM -> P(=arr) ----------------
// Block = (64-target tile, relation r). 8 waves x 64 lanes.
// Phase 1: each wave gathers 8 targets sequentially into bf16 LDS tile sA.
// Phase 2: MFMA GEMM sA @ sB(W^T) -> P rows (bf16), via LDS repack.
__global__ __launch_bounds__(512, 6)
void fused_gather_gemm_kernel(const u16* __restrict__ xb, const int* __restrict__ ptr,
                              const int* __restrict__ idx, const u16* __restrict__ wtb,
                              u16* __restrict__ P) {
    __shared__ u16 sB[C * 136];        // 34816 B: W^T [col][k+pad]
    __shared__ u16 sA[TILE_T * 136];   // 17408 B: agg tile -> output tile

    const int tid  = threadIdx.x;
    const int tile = blockIdx.x;
    const int r    = blockIdx.y;
    const int w    = tid >> 6;
    const int lane = tid & 63;

    // ---- stage W^T into sB (overlaps gather; barrier below covers it) ----
    {
        const uint4* src = (const uint4*)(wtb + (size_t)r * C * C);
        #pragma unroll
        for (int i = 0; i < 4; ++i) {
            const int f = tid + i * 512;        // 2048 16B-units
            const int col = f >> 4, unit = f & 15;
            *(uint4*)(sB + col * 136 + unit * 8) = src[f];
        }
    }

    // ---- phase 1: gather 8 targets per wave ----
    const int* pr = ptr + r * (TNODE + 1);
    const int* er = idx + (size_t)r * NEDGE;
    const int q  = lane >> 4;    // edge slot 0..3
    const int sl = lane & 15;    // 8-col chunk (16B)
    const u16* xcol = xb + sl * 8;

    for (int s = 0; s < 8; ++s) {
        const int tl = w * 8 + s;
        const int t  = tile * TILE_T + tl;
        f32x2 accA[4], accB[4];
        #pragma unroll
        for (int j = 0; j < 4; ++j) { accA[j] = (f32x2){0.f, 0.f}; accB[j] = (f32x2){0.f, 0.f}; }

        if (t < TNODE) {
            // clip(searchsorted(ptr,e,'right')-1, 0, T-1):
            //   t==0 owns [0, ptr[1]); t==T-1 owns [ptr[T-1], E)
            const int start = (t == 0) ? 0 : pr[t];
            const int end   = (t == TNODE - 1) ? NEDGE : pr[t + 1];

            for (int base = start; base < end; base += 64) {
                const int cnt = min(end - base, 64);
                int myi = (lane < cnt) ? er[base + lane] : 0;
                int i = 0;
                for (; i + 8 <= cnt; i += 8) {           // 8 edges/iter, 2 loads in flight/lane
                    const int sA0 = __shfl(myi, i + q);
                    const int sB0 = __shfl(myi, i + 4 + q);
                    const uint4 vA = *(const uint4*)(xcol + (size_t)sA0 * C);
                    const uint4 vB = *(const uint4*)(xcol + (size_t)sB0 * C);
                    addp(accA, vA);
                    addp(accB, vB);
                }
                if (i + 4 <= cnt) {
                    const int sA0 = __shfl(myi, i + q);
                    const uint4 vA = *(const uint4*)(xcol + (size_t)sA0 * C);
                    addp(accA, vA);
                    i += 4;
                }
                if (i < cnt) {                           // 1..3 leftover edges
                    const int rem = cnt - i;
                    const int sA0 = __shfl(myi, i + ((q < rem) ? q : 0));
                    if (q < rem) {
                        const uint4 vA = *(const uint4*)(xcol + (size_t)sA0 * C);
                        addp(accA, vA);
                    }
                }
            }
        }
        // fold 4 quarter-wave slots
        #pragma unroll
        for (int j = 0; j < 4; ++j) {
            accA[j] += accB[j];
            accA[j].x += __shfl_xor(accA[j].x, 16);
            accA[j].y += __shfl_xor(accA[j].y, 16);
            accA[j].x += __shfl_xor(accA[j].x, 32);
            accA[j].y += __shfl_xor(accA[j].y, 32);
        }
        if (q == 0) {   // 16 lanes write the full 256B row (zeros for t >= TNODE)
            uint4 o;
            o.x = pack2(accA[0].x, accA[0].y);
            o.y = pack2(accA[1].x, accA[1].y);
            o.z = pack2(accA[2].x, accA[2].y);
            o.w = pack2(accA[3].x, accA[3].y);
            *(uint4*)(sA + tl * 136 + sl * 8) = o;
        }
    }
    __syncthreads();

    // ---- phase 2: MFMA GEMM. wave w: rows (w&3)*16..+16, col-block (w>>2)*64..+64 ----
    const int wr    = (w & 3) * 16;
    const int cbase = (w >> 2) * 4;      // cf offset (cf = 16-col block)
    const int fr    = lane & 15;
    const int fq    = lane >> 4;

    f32x4 acc[4];
    #pragma unroll
    for (int cf = 0; cf < 4; ++cf) acc[cf] = (f32x4){0.f, 0.f, 0.f, 0.f};

    #pragma unroll
    for (int ks = 0; ks < 4; ++ks) {
        const bf16x8 a = *(const bf16x8*)(sA + (wr + fr) * 136 + ks * 32 + fq * 8);
        #pragma unroll
        for (int cf = 0; cf < 4; ++cf) {
            const bf16x8 b = *(const bf16x8*)(sB + ((cbase + cf) * 16 + fr) * 136 + ks * 32 + fq * 8);
            acc[cf] = __builtin_amdgcn_mfma_f32_16x16x32_bf16(a, b, acc[cf], 0, 0, 0);
        }
    }
    __syncthreads();   // all A-frag reads done before D overwrites sA

    // D -> sA as bf16 (C/D layout: col=lane&15, row=(lane>>4)*4+reg)
    #pragma unroll
    for (int cf = 0; cf < 4; ++cf) {
        #pragma unroll
        for (int j = 0; j < 4; ++j) {
            const int row = wr + fq * 4 + j;
            sA[row * 136 + (cbase + cf) * 16 + fr] = f2bf(acc[cf][j]);
        }
    }
    __syncthreads();

    // coalesced store into P
    #pragma unroll
    for (int i = 0; i < 2; ++i) {
        const int f = tid + i * 512;        // 1024 16B-units
        const int row = f >> 4, unit = f & 15;
        const int t = tile * TILE_T + row;
        if (t < TNODE)
            *(uint4*)(P + ((size_t)r * TNODE + t) * C + unit * 8) =
                *(const uint4*)(sA + row * 136 + unit * 8);
    }
}

// ---------------- kernel 3: per-node gather of bf16 arr rows (no atomics) ----------------
__global__ __launch_bounds__(256)
void out_gather_kernel(const u16* __restrict__ P, const int* __restrict__ offsets,
                       const int* __restrict__ count, const int* __restrict__ list,
                       float* __restrict__ out) {
    const int lane = threadIdx.x & 63;
    const int n = blockIdx.x * 4 + (threadIdx.x >> 6);
    if (n >= NNODE) return;
    const int st = offsets[n];
    const int en = st + count[n];
    float2 a0 = make_float2(0.f, 0.f), a1 = make_float2(0.f, 0.f);
    int i = st;
    for (; i + 2 <= en; i += 2) {
        const u32 v0 = ((const u32*)(P + (size_t)list[i] * C))[lane];
        const u32 v1 = ((const u32*)(P + (size_t)list[i + 1] * C))[lane];
        const float2 f0 = unpack_bf2(v0), f1 = unpack_bf2(v1);
        a0.x += f0.x; a0.y += f0.y;
        a1.x += f1.x; a1.y += f1.y;
    }
    if (i < en) {
        const float2 f0 = unpack_bf2(((const u32*)(P + (size_t)list[i] * C))[lane]);
        a0.x += f0.x; a0.y += f0.y;
    }
    a0.x += a1.x; a0.y += a1.y;
    ((float2*)(out + (size_t)n * C))[lane] = a0;
}

// ---------------- fallback: round-1 fused kernel (used only if ws too small) ----------------
__device__ __forceinline__ void add4(float4& acc, const float4& b) {
    acc.x += b.x; acc.y += b.y; acc.z += b.z; acc.w += b.w;
}
__global__ __launch_bounds__(256, 1)
void rgcn_fused_kernel(const float* __restrict__ x, const float* __restrict__ w,
                       const int* __restrict__ ptr, const int* __restrict__ idx,
                       const int* __restrict__ tgt, float* __restrict__ out) {
    __shared__ float sW[C * C];
    __shared__ float sAgg[TILE_T][C + 4];
    const int tid = threadIdx.x, tile = blockIdx.x, r = blockIdx.y;
    {
        const float4* src = (const float4*)(w + (size_t)r * C * C);
        float4* dst = (float4*)sW;
        #pragma unroll
        for (int i = 0; i < 16; ++i) dst[tid + i * 256] = src[tid + i * 256];
    }
    {
        const int tl = tid >> 2, g = tid & 3;
        const int t = tile * TILE_T + tl;
        float4 a[8];
        #pragma unroll
        for (int j = 0; j < 8; ++j) a[j] = make_float4(0.f, 0.f, 0.f, 0.f);
        if (t < TNODE) {
            const int* pr = ptr + (size_t)r * (TNODE + 1);
            const int* er = idx + (size_t)r * NEDGE;
            int e = (t == 0) ? 0 : pr[t];
            const int end = (t == TNODE - 1) ? NEDGE : pr[t + 1];
            for (; e < end; ++e) {
                const int s0 = er[e];
                const float4* r0 = (const float4*)(x + (size_t)s0 * C) + g * 8;
                #pragma unroll
                for (int j = 0; j < 8; ++j) add4(a[j], r0[j]);
            }
        }
        float* rowp = &sAgg[tl][g * 32];
        #pragma unroll
        for (int j = 0; j < 8; ++j) ((float4*)rowp)[j] = a[j];
    }
    __syncthreads();
    const int tg = tid >> 4, cg = tid & 15;
    float4 acc0[4], acc1[4];
    #pragma unroll
    for (int i = 0; i < 4; ++i) {
        acc0[i] = make_float4(0.f, 0.f, 0.f, 0.f);
        acc1[i] = make_float4(0.f, 0.f, 0.f, 0.f);
    }
    for (int k4 = 0; k4 < C / 4; ++k4) {
        float4 av[4];
        #pragma unroll
        for (int i = 0; i < 4; ++i) av[i] = *(const float4*)&sAgg[tg * 4 + i][k4 * 4];
        #pragma unroll
        for (int kk = 0; kk < 4; ++kk) {
            const int k = k4 * 4 + kk;
            const float4 w0 = *(const float4*)&sW[k * C + cg * 4];
            const float4 w1 = *(const float4*)&sW[k * C + 64 + cg * 4];
            #pragma unroll
            for (int i = 0; i < 4; ++i) {
                const float a = ((const float*)&av[i])[kk];
                fma4(acc0[i], a, w0.x, w0.y, w0.z, w0.w);
                fma4(acc1[i], a, w1.x, w1.y, w1.z, w1.w);
            }
        }
    }
    const int* tr = tgt + (size_t)r * TNODE;
    #pragma unroll
    for (int i = 0; i < 4; ++i) {
        const int t = tile * TILE_T + tg * 4 + i;
        if (t < TNODE) {
            const int node = tr[t];
            float* ob = out + (size_t)node * C + cg * 4;
            unsafeAtomicAdd(ob + 0, acc0[i].x);  unsafeAtomicAdd(ob + 1, acc0[i].y);
            unsafeAtomicAdd(ob + 2, acc0[i].z);  unsafeAtomicAdd(ob + 3, acc0[i].w);
            unsafeAtomicAdd(ob + 64, acc1[i].x); unsafeAtomicAdd(ob + 65, acc1[i].y);
            unsafeAtomicAdd(ob + 66, acc1[i].z); unsafeAtomicAdd(ob + 67, acc1[i].w);
        }
    }
}

extern "C" void kernel_launch(void* const* d_in, const int* in_sizes, int n_in,
                              void* d_out, int out_size, void* d_ws, size_t ws_size,
                              hipStream_t stream) {
    const float* x   = (const float*)d_in[0];
    const float* w   = (const float*)d_in[1];
    const int*   ptr = (const int*)d_in[2];
    const int*   idx = (const int*)d_in[3];
    const int*   tgt = (const int*)d_in[4];
    float* out = (float*)d_out;

    // workspace layout (all offsets 16B-aligned)
    const size_t P_OFF    = 0;                     // 400000*128*2 = 102,400,000
    const size_t XB_OFF   = 104000000;             // 25,600,000
    const size_t WTB_OFF  = 130000000;             //    262,144
    const size_t CNT_OFF  = 131000000;             //    400,000
    const size_t OFFS_OFF = 131500000;
    const size_t CUR_OFF  = 132000000;
    const size_t BSUM_OFF = 132500000;
    const size_t LIST_OFF = 133000000;             //  1,600,000 -> ends 134.6 MB
    const size_t WS_NEED  = 135000000;

    if (ws_size >= WS_NEED) {
        char* base = (char*)d_ws;
        u16*   P       = (u16*)(base + P_OFF);
        u16*   xb      = (u16*)(base + XB_OFF);
        u16*   wtb     = (u16*)(base + WTB_OFF);
        int*   count   = (int*)(base + CNT_OFF);
        int*   offsets = (int*)(base + OFFS_OFF);
        int*   cursor  = (int*)(base + CUR_OFF);
        int*   bsum    = (int*)(base + BSUM_OFF);
        int*   list    = (int*)(base + LIST_OFF);

        convert_x_kernel<<<2048, 256, 0, stream>>>(x, xb, NNODE * C / 4);
        convert_w_kernel<<<(NREL * C * C + 255) / 256, 256, 0, stream>>>(w, wtb);

        hipMemsetAsync(count, 0, NNODE * sizeof(int), stream);
        hist_kernel<<<(NENT + 255) / 256, 256, 0, stream>>>(tgt, count);
        scan1_kernel<<<NB_SCAN, 256, 0, stream>>>(count, bsum);
        scan2_kernel<<<1, 512, 0, stream>>>(bsum);
        scan3_kernel<<<NB_SCAN, 256, 0, stream>>>(count, bsum, offsets, cursor);
        fill_kernel<<<(NENT + 255) / 256, 256, 0, stream>>>(tgt, cursor, list);

        dim3 grid(NTILE, NREL);
        fused_gather_gemm_kernel<<<grid, 512, 0, stream>>>(xb, ptr, idx, wtb, P);

        out_gather_kernel<<<(NNODE + 3) / 4, 256, 0, stream>>>(P, offsets, count, list, out);
    } else {
        hipMemsetAsync(out, 0, (size_t)NNODE * C * sizeof(float), stream);
        dim3 grid(NTILE, NREL);
        rgcn_fused_kernel<<<grid, 256, 0, stream>>>(x, w, ptr, idx, tgt, out);
    }
}

// Round 8
// 345.637 us; speedup vs baseline: 3.8325x; 1.0170x over previous
//
#include <hip/hip_runtime.h>

#define NREL 8
#define NNODE 100000
#define TNODE 50000
#define NEDGE 800000
#define C 128
#define TILE_T 64
#define NTILE ((TNODE + TILE_T - 1) / TILE_T)   // 782
#define NENT (NREL * TNODE)                     // 400000 scatter entries
#define NB_SCAN ((NNODE + 255) / 256)           // 391

typedef unsigned int u32;
typedef unsigned short u16;
typedef __attribute__((ext_vector_type(8))) short bf16x8;
typedef __attribute__((ext_vector_type(4))) float f32x4;
typedef __attribute__((ext_vector_type(2))) float f32x2;

__device__ __forceinline__ float bf2f(u16 h) {
    union { u32 u; float f; } c; c.u = ((u32)h) << 16; return c.f;
}
__device__ __forceinline__ u16 f2bf(float f) {
    union { float f; u32 u; } c; c.f = f;
    u32 u = c.u + 0x7FFFu + ((c.u >> 16) & 1u);   // RNE
    return (u16)(u >> 16);
}
__device__ __forceinline__ u32 pack2(float a, float b) {
    return (u32)f2bf(a) | ((u32)f2bf(b) << 16);
}
__device__ __forceinline__ float2 unpack_bf2(u32 p) {
    union { u32 u; float f; } a, b;
    a.u = p << 16; b.u = p & 0xFFFF0000u;
    return make_float2(a.f, b.f);
}
__device__ __forceinline__ f32x2 bits2(u32 p) {
    union { u32 u[2]; f32x2 f; } c;
    c.u[0] = p << 16; c.u[1] = p & 0xFFFF0000u;
    return c.f;
}
__device__ __forceinline__ void addp(f32x2* a, uint4 v) {   // 8 bf16 cols -> 4 pk-adds
    a[0] += bits2(v.x); a[1] += bits2(v.y);
    a[2] += bits2(v.z); a[3] += bits2(v.w);
}
__device__ __forceinline__ void fma4(float4& acc, float a, float w0, float w1, float w2, float w3) {
    acc.x = fmaf(a, w0, acc.x);
    acc.y = fmaf(a, w1, acc.y);
    acc.z = fmaf(a, w2, acc.z);
    acc.w = fmaf(a, w3, acc.w);
}

// ---------------- kernel 1a: x f32 -> bf16 ----------------
__global__ __launch_bounds__(256)
void convert_x_kernel(const float* __restrict__ x, u16* __restrict__ xb, int n4) {
    int i = blockIdx.x * 256 + threadIdx.x;
    const int stride = gridDim.x * 256;
    for (; i < n4; i += stride) {
        const float4 v = ((const float4*)x)[i];
        ushort4 o;
        o.x = f2bf(v.x); o.y = f2bf(v.y); o.z = f2bf(v.z); o.w = f2bf(v.w);
        ((ushort4*)xb)[i] = o;
    }
}

// ---------------- kernel 1b: W f32 [r][k][c] -> bf16 W^T [r][c][k] ----------------
__global__ __launch_bounds__(256)
void convert_w_kernel(const float* __restrict__ w, u16* __restrict__ wtb) {
    const int o = blockIdx.x * 256 + threadIdx.x;   // enumerates (r, c, k), k inner
    if (o < NREL * C * C) {
        const int r = o >> 14, rem = o & 16383, cc = rem >> 7, k = rem & 127;
        wtb[o] = f2bf(w[(r << 14) + k * C + cc]);
    }
}

// ---------------- inverted-index build ----------------
__global__ __launch_bounds__(256)
void hist_kernel(const int* __restrict__ tgt, int* __restrict__ count) {
    const int g = blockIdx.x * 256 + threadIdx.x;
    if (g < NENT) atomicAdd(&count[tgt[g]], 1);
}

__global__ __launch_bounds__(256)
void scan1_kernel(const int* __restrict__ count, int* __restrict__ bsum) {
    __shared__ int s[256];
    const int tid = threadIdx.x;
    const int i = blockIdx.x * 256 + tid;
    s[tid] = (i < NNODE) ? count[i] : 0;
    __syncthreads();
    for (int st = 128; st > 0; st >>= 1) {
        if (tid < st) s[tid] += s[tid + st];
        __syncthreads();
    }
    if (tid == 0) bsum[blockIdx.x] = s[0];
}

__global__ __launch_bounds__(512)
void scan2_kernel(int* __restrict__ bsum) {   // 1 block, exclusive scan of NB_SCAN partials
    __shared__ int s[512];
    const int tid = threadIdx.x;
    const int v = (tid < NB_SCAN) ? bsum[tid] : 0;
    s[tid] = v;
    __syncthreads();
    for (int st = 1; st < 512; st <<= 1) {
        const int t = (tid >= st) ? s[tid - st] : 0;
        __syncthreads();
        s[tid] += t;
        __syncthreads();
    }
    if (tid < NB_SCAN) bsum[tid] = s[tid] - v;   // exclusive
}

__global__ __launch_bounds__(256)
void scan3_kernel(const int* __restrict__ count, const int* __restrict__ bsum,
                  int* __restrict__ offsets, int* __restrict__ cursor) {
    __shared__ int s[256];
    const int tid = threadIdx.x;
    const int i = blockIdx.x * 256 + tid;
    const int v = (i < NNODE) ? count[i] : 0;
    s[tid] = v;
    __syncthreads();
    for (int st = 1; st < 256; st <<= 1) {
        const int t = (tid >= st) ? s[tid - st] : 0;
        __syncthreads();
        s[tid] += t;
        __syncthreads();
    }
    if (i < NNODE) {
        const int off = bsum[blockIdx.x] + s[tid] - v;   // exclusive prefix
        offsets[i] = off;
        cursor[i]  = off;
    }
}

__global__ __launch_bounds__(256)
void fill_kernel(const int* __restrict__ tgt, int* __restrict__ cursor, int* __restrict__ list) {
    const int g = blockIdx.x * 256 + threadIdx.x;
    if (g < NENT) {
        const int pos = atomicAdd(&cursor[tgt[g]], 1);
        list[pos] = g;
    }
}

// ---------------- kernel 2: FUSED gather-sum + MFMA GEMM -> P(=arr) ----------------
// Block = (64-target tile, relation r). 8 waves x 64 lanes.
// Phase 1: waves pop targets from an LDS ticket queue (dynamic balance) and
//          gather into bf16 LDS tile sA.
// Phase 2: MFMA GEMM sA @ sB(W^T) -> P rows (bf16), via LDS repack.
__global__ __launch_bounds__(512, 6)
void fused_gather_gemm_kernel(const u16* __restrict__ xb, const int* __restrict__ ptr,
                              const int* __restrict__ idx, const u16* __restrict__ wtb,
                              u16* __restrict__ P) {
    __shared__ u16 sB[C * 136];        // 34816 B: W^T [col][k+pad]
    __shared__ u16 sA[TILE_T * 136];   // 17408 B: agg tile -> output tile
    __shared__ int qcount;             // dynamic target ticket

    const int tid  = threadIdx.x;
    const int tile = blockIdx.x;
    const int r    = blockIdx.y;
    const int w    = tid >> 6;
    const int lane = tid & 63;

    // ---- stage W^T into sB (overlaps gather; pre-GEMM barrier covers it) ----
    {
        const uint4* src = (const uint4*)(wtb + (size_t)r * C * C);
        #pragma unroll
        for (int i = 0; i < 4; ++i) {
            const int f = tid + i * 512;        // 2048 16B-units
            const int col = f >> 4, unit = f & 15;
            *(uint4*)(sB + col * 136 + unit * 8) = src[f];
        }
    }
    if (tid == 0) qcount = 0;
    __syncthreads();   // qcount visible to all waves

    // ---- phase 1: dynamic gather, one target per queue pop ----
    const int* pr = ptr + r * (TNODE + 1);
    const int* er = idx + (size_t)r * NEDGE;
    const int q  = lane >> 4;    // edge slot 0..3
    const int sl = lane & 15;    // 8-col chunk (16B)
    const u16* xcol = xb + sl * 8;

    for (;;) {
        int tl;
        if (lane == 0) tl = atomicAdd(&qcount, 1);
        tl = __shfl(tl, 0);
        if (tl >= TILE_T) break;

        const int t = tile * TILE_T + tl;
        f32x2 accA[4], accB[4];
        #pragma unroll
        for (int j = 0; j < 4; ++j) { accA[j] = (f32x2){0.f, 0.f}; accB[j] = (f32x2){0.f, 0.f}; }

        if (t < TNODE) {
            // clip(searchsorted(ptr,e,'right')-1, 0, T-1):
            //   t==0 owns [0, ptr[1]); t==T-1 owns [ptr[T-1], E)
            const int start = (t == 0) ? 0 : pr[t];
            const int end   = (t == TNODE - 1) ? NEDGE : pr[t + 1];

            for (int base = start; base < end; base += 64) {
                const int cnt = min(end - base, 64);
                int myi = (lane < cnt) ? er[base + lane] : 0;
                int i = 0;
                for (; i + 8 <= cnt; i += 8) {           // 8 edges/iter, 2 loads in flight/lane
                    const int sA0 = __shfl(myi, i + q);
                    const int sB0 = __shfl(myi, i + 4 + q);
                    const uint4 vA = *(const uint4*)(xcol + (size_t)sA0 * C);
                    const uint4 vB = *(const uint4*)(xcol + (size_t)sB0 * C);
                    addp(accA, vA);
                    addp(accB, vB);
                }
                if (i + 4 <= cnt) {
                    const int sA0 = __shfl(myi, i + q);
                    const uint4 vA = *(const uint4*)(xcol + (size_t)sA0 * C);
                    addp(accA, vA);
                    i += 4;
                }
                if (i < cnt) {                           // 1..3 leftover edges
                    const int rem = cnt - i;
                    const int sA0 = __shfl(myi, i + ((q < rem) ? q : 0));
                    if (q < rem) {
                        const uint4 vA = *(const uint4*)(xcol + (size_t)sA0 * C);
                        addp(accA, vA);
                    }
                }
            }
        }
        // fold 4 quarter-wave slots
        #pragma unroll
        for (int j = 0; j < 4; ++j) {
            accA[j] += accB[j];
            accA[j].x += __shfl_xor(accA[j].x, 16);
            accA[j].y += __shfl_xor(accA[j].y, 16);
            accA[j].x += __shfl_xor(accA[j].x, 32);
            accA[j].y += __shfl_xor(accA[j].y, 32);
        }
        if (q == 0) {   // 16 lanes write the full 256B row (zeros for t >= TNODE)
            uint4 o;
            o.x = pack2(accA[0].x, accA[0].y);
            o.y = pack2(accA[1].x, accA[1].y);
            o.z = pack2(accA[2].x, accA[2].y);
            o.w = pack2(accA[3].x, accA[3].y);
            *(uint4*)(sA + tl * 136 + sl * 8) = o;
        }
    }
    __syncthreads();

    // ---- phase 2: MFMA GEMM. wave w: rows (w&3)*16..+16, col-block (w>>2)*64..+64 ----
    const int wr    = (w & 3) * 16;
    const int cbase = (w >> 2) * 4;      // cf offset (cf = 16-col block)
    const int fr    = lane & 15;
    const int fq    = lane >> 4;

    f32x4 acc[4];
    #pragma unroll
    for (int cf = 0; cf < 4; ++cf) acc[cf] = (f32x4){0.f, 0.f, 0.f, 0.f};

    #pragma unroll
    for (int ks = 0; ks < 4; ++ks) {
        const bf16x8 a = *(const bf16x8*)(sA + (wr + fr) * 136 + ks * 32 + fq * 8);
        #pragma unroll
        for (int cf = 0; cf < 4; ++cf) {
            const bf16x8 b = *(const bf16x8*)(sB + ((cbase + cf) * 16 + fr) * 136 + ks * 32 + fq * 8);
            acc[cf] = __builtin_amdgcn_mfma_f32_16x16x32_bf16(a, b, acc[cf], 0, 0, 0);
        }
    }
    __syncthreads();   // all A-frag reads done before D overwrites sA

    // D -> sA as bf16 (C/D layout: col=lane&15, row=(lane>>4)*4+reg)
    #pragma unroll
    for (int cf = 0; cf < 4; ++cf) {
        #pragma unroll
        for (int j = 0; j < 4; ++j) {
            const int row = wr + fq * 4 + j;
            sA[row * 136 + (cbase + cf) * 16 + fr] = f2bf(acc[cf][j]);
        }
    }
    __syncthreads();

    // coalesced store into P
    #pragma unroll
    for (int i = 0; i < 2; ++i) {
        const int f = tid + i * 512;        // 1024 16B-units
        const int row = f >> 4, unit = f & 15;
        const int t = tile * TILE_T + row;
        if (t < TNODE)
            *(uint4*)(P + ((size_t)r * TNODE + t) * C + unit * 8) =
                *(const uint4*)(sA + row * 136 + unit * 8);
    }
}

// ---------------- kernel 3: per-node gather of bf16 arr rows (no atomics) ----------------
__global__ __launch_bounds__(256)
void out_gather_kernel(const u16* __restrict__ P, const int* __restrict__ offsets,
                       const int* __restrict__ count, const int* __restrict__ list,
                       float* __restrict__ out) {
    const int lane = threadIdx.x & 63;
    const int n = blockIdx.x * 4 + (threadIdx.x >> 6);
    if (n >= NNODE) return;
    const int st = offsets[n];
    const int en = st + count[n];
    float2 a0 = make_float2(0.f, 0.f), a1 = make_float2(0.f, 0.f);
    int i = st;
    for (; i + 2 <= en; i += 2) {
        const u32 v0 = ((const u32*)(P + (size_t)list[i] * C))[lane];
        const u32 v1 = ((const u32*)(P + (size_t)list[i + 1] * C))[lane];
        const float2 f0 = unpack_bf2(v0), f1 = unpack_bf2(v1);
        a0.x += f0.x; a0.y += f0.y;
        a1.x += f1.x; a1.y += f1.y;
    }
    if (i < en) {
        const float2 f0 = unpack_bf2(((const u32*)(P + (size_t)list[i] * C))[lane]);
        a0.x += f0.x; a0.y += f0.y;
    }
    a0.x += a1.x; a0.y += a1.y;
    ((float2*)(out + (size_t)n * C))[lane] = a0;
}

// ---------------- fallback: round-1 fused kernel (used only if ws too small) ----------------
__device__ __forceinline__ void add4(float4& acc, const float4& b) {
    acc.x += b.x; acc.y += b.y; acc.z += b.z; acc.w += b.w;
}
__global__ __launch_bounds__(256, 1)
void rgcn_fused_kernel(const float* __restrict__ x, const float* __restrict__ w,
                       const int* __restrict__ ptr, const int* __restrict__ idx,
                       const int* __restrict__ tgt, float* __restrict__ out) {
    __shared__ float sW[C * C];
    __shared__ float sAgg[TILE_T][C + 4];
    const int tid = threadIdx.x, tile = blockIdx.x, r = blockIdx.y;
    {
        const float4* src = (const float4*)(w + (size_t)r * C * C);
        float4* dst = (float4*)sW;
        #pragma unroll
        for (int i = 0; i < 16; ++i) dst[tid + i * 256] = src[tid + i * 256];
    }
    {
        const int tl = tid >> 2, g = tid & 3;
        const int t = tile * TILE_T + tl;
        float4 a[8];
        #pragma unroll
        for (int j = 0; j < 8; ++j) a[j] = make_float4(0.f, 0.f, 0.f, 0.f);
        if (t < TNODE) {
            const int* pr = ptr + (size_t)r * (TNODE + 1);
            const int* er = idx + (size_t)r * NEDGE;
            int e = (t == 0) ? 0 : pr[t];
            const int end = (t == TNODE - 1) ? NEDGE : pr[t + 1];
            for (; e < end; ++e) {
                const int s0 = er[e];
                const float4* r0 = (const float4*)(x + (size_t)s0 * C) + g * 8;
                #pragma unroll
                for (int j = 0; j < 8; ++j) add4(a[j], r0[j]);
            }
        }
        float* rowp = &sAgg[tl][g * 32];
        #pragma unroll
        for (int j = 0; j < 8; ++j) ((float4*)rowp)[j] = a[j];
    }
    __syncthreads();
    const int tg = tid >> 4, cg = tid & 15;
    float4 acc0[4], acc1[4];
    #pragma unroll
    for (int i = 0; i < 4; ++i) {
        acc0[i] = make_float4(0.f, 0.f, 0.f, 0.f);
        acc1[i] = make_float4(0.f, 0.f, 0.f, 0.f);
    }
    for (int k4 = 0; k4 < C / 4; ++k4) {
        float4 av[4];
        #pragma unroll
        for (int i = 0; i < 4; ++i) av[i] = *(const float4*)&sAgg[tg * 4 + i][k4 * 4];
        #pragma unroll
        for (int kk = 0; kk < 4; ++kk) {
            const int k = k4 * 4 + kk;
            const float4 w0 = *(const float4*)&sW[k * C + cg * 4];
            const float4 w1 = *(const float4*)&sW[k * C + 64 + cg * 4];
            #pragma unroll
            for (int i = 0; i < 4; ++i) {
                const float a = ((const float*)&av[i])[kk];
                fma4(acc0[i], a, w0.x, w0.y, w0.z, w0.w);
                fma4(acc1[i], a, w1.x, w1.y, w1.z, w1.w);
            }
        }
    }
    const int* tr = tgt + (size_t)r * TNODE;
    #pragma unroll
    for (int i = 0; i < 4; ++i) {
        const int t = tile * TILE_T + tg * 4 + i;
        if (t < TNODE) {
            const int node = tr[t];
            float* ob = out + (size_t)node * C + cg * 4;
            unsafeAtomicAdd(ob + 0, acc0[i].x);  unsafeAtomicAdd(ob + 1, acc0[i].y);
            unsafeAtomicAdd(ob + 2, acc0[i].z);  unsafeAtomicAdd(ob + 3, acc0[i].w);
            unsafeAtomicAdd(ob + 64, acc1[i].x); unsafeAtomicAdd(ob + 65, acc1[i].y);
            unsafeAtomicAdd(ob + 66, acc1[i].z); unsafeAtomicAdd(ob + 67, acc1[i].w);
        }
    }
}

extern "C" void kernel_launch(void* const* d_in, const int* in_sizes, int n_in,
                              void* d_out, int out_size, void* d_ws, size_t ws_size,
                              hipStream_t stream) {
    const float* x   = (const float*)d_in[0];
    const float* w   = (const float*)d_in[1];
    const int*   ptr = (const int*)d_in[2];
    const int*   idx = (const int*)d_in[3];
    const int*   tgt = (const int*)d_in[4];
    float* out = (float*)d_out;

    // workspace layout (all offsets 16B-aligned)
    const size_t P_OFF    = 0;                     // 400000*128*2 = 102,400,000
    const size_t XB_OFF   = 104000000;             // 25,600,000
    const size_t WTB_OFF  = 130000000;             //    262,144
    const size_t CNT_OFF  = 131000000;             //    400,000
    const size_t OFFS_OFF = 131500000;
    const size_t CUR_OFF  = 132000000;
    const size_t BSUM_OFF = 132500000;
    const size_t LIST_OFF = 133000000;             //  1,600,000 -> ends 134.6 MB
    const size_t WS_NEED  = 135000000;

    if (ws_size >= WS_NEED) {
        char* base = (char*)d_ws;
        u16*   P       = (u16*)(base + P_OFF);
        u16*   xb      = (u16*)(base + XB_OFF);
        u16*   wtb     = (u16*)(base + WTB_OFF);
        int*   count   = (int*)(base + CNT_OFF);
        int*   offsets = (int*)(base + OFFS_OFF);
        int*   cursor  = (int*)(base + CUR_OFF);
        int*   bsum    = (int*)(base + BSUM_OFF);
        int*   list    = (int*)(base + LIST_OFF);

        convert_x_kernel<<<2048, 256, 0, stream>>>(x, xb, NNODE * C / 4);
        convert_w_kernel<<<(NREL * C * C + 255) / 256, 256, 0, stream>>>(w, wtb);

        hipMemsetAsync(count, 0, NNODE * sizeof(int), stream);
        hist_kernel<<<(NENT + 255) / 256, 256, 0, stream>>>(tgt, count);
        scan1_kernel<<<NB_SCAN, 256, 0, stream>>>(count, bsum);
        scan2_kernel<<<1, 512, 0, stream>>>(bsum);
        scan3_kernel<<<NB_SCAN, 256, 0, stream>>>(count, bsum, offsets, cursor);
        fill_kernel<<<(NENT + 255) / 256, 256, 0, stream>>>(tgt, cursor, list);

        dim3 grid(NTILE, NREL);
        fused_gather_gemm_kernel<<<grid, 512, 0, stream>>>(xb, ptr, idx, wtb, P);

        out_gather_kernel<<<(NNODE + 3) / 4, 256, 0, stream>>>(P, offsets, count, list, out);
    } else {
        hipMemsetAsync(out, 0, (size_t)NNODE * C * sizeof(float), stream);
        dim3 grid(NTILE, NREL);
        rgcn_fused_kernel<<<grid, 256, 0, stream>>>(x, w, ptr, idx, tgt, out);
    }
}